// Round 13
// baseline (53228.735 us; speedup 1.0000x reference)
//
#include <hip/hip_runtime.h>
#include <math.h>
#include <cstddef>

#define Bn 8
#define Cc 512
#define Nn 4096
#define Kk 3
#define Pp 16
#define NMAT 48
#define MSZ (Cc*Cc)
#define ALPHA_C 0.6f
#define BETA_C 0.4f
#define GAMMA_C 0.1
#define POW_ITERS 8
#define NS64_ITERS 26
#define NSB6 6

__device__ __forceinline__ const float* Fbase(const float* cont, const float* sty, int p){
  return (p < Bn) ? (cont + (size_t)p*Cc*Nn) : (sty + (size_t)(p-Bn)*Cc*Nn);
}

// ===== ideal-fp32 k-means: exact arithmetic, rounded where the references round =====

// fp32 centroids init (input pixels, already fp32 exact)
__global__ void k_init_cent32(const float* __restrict__ cont, const float* __restrict__ sty,
                              float* __restrict__ cent32){
  int m = blockIdx.x; int p = m/Kk, k = m%Kk;
  const int ninit[3] = {0, 2047, 4095};
  const float* F = Fbase(cont, sty, p);
  int c = threadIdx.x;
  cent32[(size_t)m*Cc + c] = F[(size_t)c*Nn + ninit[k]];
}

// xsq32[p][n] = round_f32( exact sum of x^2 )  (fp64 accumulation)
__global__ __launch_bounds__(256) void k_xsq32(const float* __restrict__ cont, const float* __restrict__ sty,
                                               float* __restrict__ xsq32){
  int p = blockIdx.x;
  int n = blockIdx.y*256 + threadIdx.x;
  const float* F = Fbase(cont, sty, p);
  double s = 0.0;
  for (int c=0; c<Cc; c++){ double v = (double)F[(size_t)c*Nn + n]; s += v*v; }
  xsq32[p*Nn + n] = (float)s;
}

// csq32[m] = round_f32( exact sum of cent32^2 )
__global__ void k_csq32(const float* __restrict__ cent32, float* __restrict__ csq32){
  int m = threadIdx.x;
  if (m >= NMAT) return;
  const float* c = cent32 + (size_t)m*Cc;
  double s = 0.0;
  for (int i=0;i<Cc;i++){ double v = (double)c[i]; s += v*v; }
  csq32[m] = (float)s;
}

// assignment with ideal-fp32 distances:
// d32 = round_f32(exact dot); D = fl(fl(xs32 - 2*d32) + cs32); first-index argmin
__global__ __launch_bounds__(256) void k_assign_i32(const float* __restrict__ cont, const float* __restrict__ sty,
                                                    const float* __restrict__ cent32, const float* __restrict__ csq32,
                                                    const float* __restrict__ xsq32, int* __restrict__ assign){
  __shared__ float cl[Kk][Cc];
  int p = blockIdx.x, t = threadIdx.x;
  const float* F = Fbase(cont, sty, p);
  for (int i=t; i<Kk*Cc; i+=256) ((float*)cl)[i] = cent32[(size_t)p*Kk*Cc + i];
  __syncthreads();
  float cs0 = csq32[p*Kk+0], cs1 = csq32[p*Kk+1], cs2 = csq32[p*Kk+2];
  int n = blockIdx.y*256 + t;
  const float* col = F + n;
  double d0=0.0, d1=0.0, d2=0.0;
  for (int c=0; c<Cc; c++){
    double f = (double)col[(size_t)c*Nn];
    d0 += f*(double)cl[0][c];
    d1 += f*(double)cl[1][c];
    d2 += f*(double)cl[2][c];
  }
  float f0 = (float)d0, f1 = (float)d1, f2 = (float)d2;
  float xs = xsq32[p*Nn + n];
  float D0, D1, D2;
  {
    #pragma clang fp contract(off)
    D0 = (xs - 2.f*f0) + cs0;
    D1 = (xs - 2.f*f1) + cs1;
    D2 = (xs - 2.f*f2) + cs2;
  }
  int a = 0; float best = D0;
  if (D1 < best){ best = D1; a = 1; }
  if (D2 < best){ best = D2; a = 2; }
  assign[p*Nn + n] = a;
}

// per-cluster sums (fp64 exact) + counts
__global__ __launch_bounds__(256) void k_update64(const float* __restrict__ cont, const float* __restrict__ sty,
                                                  const int* __restrict__ assign,
                                                  double* __restrict__ csum, float* __restrict__ cntf){
  __shared__ unsigned char al[Nn];
  __shared__ int ri[256];
  int p = blockIdx.x, cg = blockIdx.y, t = threadIdx.x;
  const float* F = Fbase(cont, sty, p);
  for (int i=t; i<Nn; i+=256) al[i] = (unsigned char)assign[p*Nn+i];
  __syncthreads();
  int wave = t>>6, lane = t&63;
  for (int rr=0; rr<16; rr++){
    int r = cg*64 + wave*16 + rr;
    const float* row = F + (size_t)r*Nn;
    double s0=0.0,s1=0.0,s2=0.0;
    for (int n=lane; n<Nn; n+=64){
      double f = (double)row[n]; int a = al[n];
      s0 += (a==0)?f:0.0; s1 += (a==1)?f:0.0; s2 += (a==2)?f:0.0;
    }
    for (int off=32; off>0; off>>=1){
      s0 += __shfl_xor(s0,off); s1 += __shfl_xor(s1,off); s2 += __shfl_xor(s2,off);
    }
    if (lane==0){
      csum[((size_t)p*Kk+0)*Cc + r] = s0;
      csum[((size_t)p*Kk+1)*Cc + r] = s1;
      csum[((size_t)p*Kk+2)*Cc + r] = s2;
    }
  }
  if (cg==0){
    int c0=0,c1=0,c2=0;
    for (int n=t;n<Nn;n+=256){ int a=al[n]; c0+=(a==0); c1+=(a==1); c2+=(a==2); }
    for (int k=0;k<3;k++){
      int v = (k==0)?c0:((k==1)?c1:c2);
      ri[t] = v; __syncthreads();
      for (int off=128; off>0; off>>=1){ if(t<off) ri[t]+=ri[t+off]; __syncthreads(); }
      if (t==0) cntf[p*Kk+k] = (float)ri[0];
      __syncthreads();
    }
  }
}

// cent32 = fl( round_f32(exact sum) / cnt )  -- the shared fp32 rounding both refs apply
__global__ void k_centupd32(const double* __restrict__ csum, const float* __restrict__ cntf,
                            float* __restrict__ cent32){
  int m = blockIdx.x, c = threadIdx.x;
  float n = cntf[m];
  if (n > 0.f){
    float s32 = (float)csum[(size_t)m*Cc + c];
    cent32[(size_t)m*Cc + c] = s32 / fmaxf(n, 1.f);
  }
}

__global__ void k_mu64(const double* __restrict__ csum, const float* __restrict__ cntf,
                       double* __restrict__ mu64, float* __restrict__ mu32, double* __restrict__ dvc){
  int m = blockIdx.x, t = threadIdx.x;
  double n = fmax((double)cntf[m], 1.0);
  double v = csum[(size_t)m*Cc+t] / n;
  mu64[(size_t)m*Cc+t] = v;
  mu32[(size_t)m*Cc+t] = (float)v;
  if (t==0) dvc[m] = 1.0 / fmax(n-1.0, 1.0);
}

// cov64 masked SYRK fp64 (64x64 tile)
__global__ __launch_bounds__(256) void k_covd64(const float* __restrict__ cont, const float* __restrict__ sty,
                                                const int* __restrict__ assign, const double* __restrict__ mu,
                                                const double* __restrict__ dvc, double* __restrict__ cov){
  __shared__ double As[16][66], Bs[16][66];
  __shared__ unsigned char al[Nn];
  int m = blockIdx.z; int p = m/Kk; int k = m%Kk;
  const float* F = Fbase(cont, sty, p);
  int t = threadIdx.x;
  for (int i=t; i<Nn; i+=256) al[i] = (unsigned char)assign[p*Nn+i];
  int i0 = blockIdx.x*64, j0 = blockIdx.y*64;
  int lr = t>>2, lc = (t&3)*4;
  int ty = t>>4, tx = t&15;
  const double* muM = mu + (size_t)m*Cc;
  double muA = muM[i0+lr];
  double muB = muM[j0+lr];
  __syncthreads();
  double acc[4][4] = {};
  for (int kt=0; kt<Nn; kt+=16){
    float4 av = *(const float4*)(F + (size_t)(i0+lr)*Nn + kt + lc);
    float4 bv = *(const float4*)(F + (size_t)(j0+lr)*Nn + kt + lc);
    double mk[4];
    #pragma unroll
    for (int u=0;u<4;u++) mk[u] = (al[kt+lc+u]==k) ? 1.0 : 0.0;
    As[lc+0][lr] = mk[0]*((double)av.x-muA);
    As[lc+1][lr] = mk[1]*((double)av.y-muA);
    As[lc+2][lr] = mk[2]*((double)av.z-muA);
    As[lc+3][lr] = mk[3]*((double)av.w-muA);
    Bs[lc+0][lr] = (double)bv.x-muB;
    Bs[lc+1][lr] = (double)bv.y-muB;
    Bs[lc+2][lr] = (double)bv.z-muB;
    Bs[lc+3][lr] = (double)bv.w-muB;
    __syncthreads();
    #pragma unroll
    for (int kk=0; kk<16; kk++){
      double aa[4], bb[4];
      #pragma unroll
      for (int i=0;i<4;i++) aa[i] = As[kk][ty*4+i];
      #pragma unroll
      for (int j=0;j<4;j++) bb[j] = Bs[kk][tx*4+j];
      #pragma unroll
      for (int i=0;i<4;i++)
        #pragma unroll
        for (int j=0;j<4;j++) acc[i][j] = fma(aa[i], bb[j], acc[i][j]);
    }
    __syncthreads();
  }
  double dv = dvc[m];
  #pragma unroll
  for (int i=0;i<4;i++){
    int gi = i0 + ty*4 + i;
    #pragma unroll
    for (int j=0;j<4;j++){
      int gj = j0 + tx*4 + j;
      double v = acc[i][j]*dv;
      if (gi==gj) v += GAMMA_C;
      cov[(size_t)m*MSZ + (size_t)gi*Cc + gj] = v;
    }
  }
}

__global__ __launch_bounds__(256) void k_power64(const double* __restrict__ cov, float* __restrict__ sarr){
  __shared__ double v[Cc], w[Cc], red[256];
  int m = blockIdx.x, t = threadIdx.x;
  const double* A = cov + (size_t)m*MSZ;
  for (int i=t;i<Cc;i+=256) v[i] = 1.0;
  __syncthreads();
  int wave = t>>6, lane = t&63;
  for (int it=0; it<POW_ITERS+1; it++){
    for (int r = wave*128; r < wave*128+128; r++){
      const double* row = A + (size_t)r*Cc;
      double pa = 0.0;
      for (int j=lane; j<Cc; j+=64) pa = fma(row[j], v[j], pa);
      for (int off=32; off>0; off>>=1) pa += __shfl_xor(pa, off);
      if (lane==0) w[r] = pa;
    }
    __syncthreads();
    if (it < POW_ITERS){
      double nn = 0.0;
      for (int i=t;i<Cc;i+=256) nn += w[i]*w[i];
      red[t]=nn; __syncthreads();
      for (int off=128;off>0;off>>=1){ if(t<off) red[t]+=red[t+off]; __syncthreads(); }
      double inv = rsqrt(fmax(red[0], 1e-300));
      __syncthreads();
      for (int i=t;i<Cc;i+=256) v[i] = w[i]*inv;
      __syncthreads();
    }
  }
  double rr = 0.0;
  for (int i=t;i<Cc;i+=256) rr += v[i]*w[i];
  red[t]=rr; __syncthreads();
  for (int off=128;off>0;off>>=1){ if(t<off) red[t]+=red[t+off]; __syncthreads(); }
  if (t==0) sarr[m] = (float)(1.3*red[0] + 1e-6);
}

__global__ __launch_bounds__(256) void k_scale_init64(const double* __restrict__ cov, const float* __restrict__ sarr,
                                                      double* __restrict__ Y, double* __restrict__ Z, int m0){
  int i = blockIdx.x, t = threadIdx.x;
  double rs = 1.0 / (double)sarr[m0+i];
  const double* src = cov + (size_t)(m0+i)*MSZ;
  size_t base = (size_t)i*MSZ;
  int j0 = blockIdx.y*8192;
  for (int j = j0 + t; j < j0 + 8192; j += 256){
    Y[base+j] = src[j]*rs;
    int r = j>>9, c = j&511;
    Z[base+j] = (r==c) ? 1.0 : 0.0;
  }
}

// fp64 batched GEMM 64x64 tile. MODE 0: C=A@B  MODE 2: C = 1.5I - 0.5(A@B)
template<int MODE>
__global__ __launch_bounds__(256) void gemm64d(const double* __restrict__ Ab, const double* __restrict__ Bb,
                                               double* __restrict__ Cb){
  __shared__ double As[16][66], Bs[16][66];
  int m = blockIdx.z;
  const double* A = Ab + (size_t)m*MSZ;
  const double* Bm = Bb + (size_t)m*MSZ;
  double* Cm = Cb + (size_t)m*MSZ;
  int t = threadIdx.x;
  int tx = t&15, ty = t>>4;
  int i0 = blockIdx.x*64, j0 = blockIdx.y*64;
  int lr = t>>2, lc = (t&3)*4;
  int bk = t>>6, bj = t&63;
  double acc[4][4] = {};
  for (int kt=0; kt<Cc; kt+=16){
    #pragma unroll
    for (int u=0;u<4;u++) As[lc+u][lr] = A[(size_t)(i0+lr)*Cc + kt + lc + u];
    #pragma unroll
    for (int u=0;u<4;u++) Bs[bk+4*u][bj] = Bm[(size_t)(kt+bk+4*u)*Cc + j0 + bj];
    __syncthreads();
    #pragma unroll
    for (int kk=0; kk<16; kk++){
      double a_[4], b_[4];
      #pragma unroll
      for (int i=0;i<4;i++) a_[i] = As[kk][ty*4+i];
      #pragma unroll
      for (int j=0;j<4;j++) b_[j] = Bs[kk][tx*4+j];
      #pragma unroll
      for (int i=0;i<4;i++)
        #pragma unroll
        for (int j=0;j<4;j++) acc[i][j] = fma(a_[i], b_[j], acc[i][j]);
    }
    __syncthreads();
  }
  #pragma unroll
  for (int i=0;i<4;i++){
    int gi = i0 + ty*4 + i;
    #pragma unroll
    for (int j=0;j<4;j++){
      int gj = j0 + tx*4 + j;
      if (MODE==0) Cm[(size_t)gi*Cc + gj] = acc[i][j];
      else         Cm[(size_t)gi*Cc + gj] = -0.5*acc[i][j] + ((gi==gj)?1.5:0.0);
    }
  }
}

__global__ __launch_bounds__(256) void k_keepC(const double* __restrict__ Zb, float* __restrict__ nsResC, int m0){
  int i = blockIdx.x, t = threadIdx.x;
  const double* src = Zb + (size_t)i*MSZ;
  float* dst = nsResC + (size_t)(m0+i)*MSZ;
  int j0 = blockIdx.y*2048;
  for (int j = j0 + t; j < j0 + 2048; j += 256) dst[j] = (float)src[j];
}

__global__ __launch_bounds__(256) void k_keepS(const double* __restrict__ Yb, float* __restrict__ styY6){
  int i = blockIdx.x, t = threadIdx.x;
  const double* src = Yb + (size_t)i*MSZ;
  float* dst = styY6 + (size_t)i*MSZ;
  int j0 = blockIdx.y*2048;
  for (int j = j0 + t; j < j0 + 2048; j += 256) dst[j] = (float)src[j];
}

// fp32 batched GEMM 128x128. MODE 2: C = sfac[m]*(A@B) + 0.4I
template<int MODE>
__global__ __launch_bounds__(256) void gemm128(const float* __restrict__ Ab, const float* __restrict__ Bb,
                                               float* __restrict__ Cb, const float* __restrict__ sfac){
  __shared__ float As[16][132], Bs[16][132];
  int m = blockIdx.z;
  const float* A = Ab + (size_t)m*MSZ;
  const float* Bm = Bb + (size_t)m*MSZ;
  float* Cm = Cb + (size_t)m*MSZ;
  int t = threadIdx.x;
  int tx = t&15, ty = t>>4;
  int i0 = blockIdx.x*128, j0 = blockIdx.y*128;
  int ar = t>>2, ac = (t&3)*4;
  int bk = t>>5, bj = (t&31)*4;
  float acc[8][8] = {};
  for (int kt=0; kt<Cc; kt+=16){
    float4 a0 = *(const float4*)(A + (size_t)(i0+ar)*Cc + kt + ac);
    float4 a1 = *(const float4*)(A + (size_t)(i0+ar+64)*Cc + kt + ac);
    float4 b0 = *(const float4*)(Bm + (size_t)(kt+bk)*Cc + j0 + bj);
    float4 b1 = *(const float4*)(Bm + (size_t)(kt+bk+8)*Cc + j0 + bj);
    As[ac+0][ar]=a0.x; As[ac+1][ar]=a0.y; As[ac+2][ar]=a0.z; As[ac+3][ar]=a0.w;
    As[ac+0][ar+64]=a1.x; As[ac+1][ar+64]=a1.y; As[ac+2][ar+64]=a1.z; As[ac+3][ar+64]=a1.w;
    *(float4*)&Bs[bk][bj] = b0;
    *(float4*)&Bs[bk+8][bj] = b1;
    __syncthreads();
    #pragma unroll
    for (int kk=0; kk<16; kk++){
      float4 x0 = *(const float4*)&As[kk][ty*8];
      float4 x1 = *(const float4*)&As[kk][ty*8+4];
      float4 y0 = *(const float4*)&Bs[kk][tx*8];
      float4 y1 = *(const float4*)&Bs[kk][tx*8+4];
      float av[8] = {x0.x,x0.y,x0.z,x0.w,x1.x,x1.y,x1.z,x1.w};
      float bv[8] = {y0.x,y0.y,y0.z,y0.w,y1.x,y1.y,y1.z,y1.w};
      #pragma unroll
      for (int i=0;i<8;i++)
        #pragma unroll
        for (int j=0;j<8;j++) acc[i][j] = fmaf(av[i], bv[j], acc[i][j]);
    }
    __syncthreads();
  }
  float sf = (MODE==2) ? sfac[m] : 0.f;
  #pragma unroll
  for (int i=0;i<8;i++){
    int gi = i0 + ty*8 + i;
    #pragma unroll
    for (int j=0;j<8;j++){
      int gj = j0 + tx*8 + j;
      float pv = acc[i][j];
      float v;
      if (MODE==2) v = sf*pv + ((gi==gj)?BETA_C:0.f);
      else         v = pv;
      Cm[(size_t)gi*Cc + gj] = v;
    }
  }
}

__global__ void k_sfac(const float* __restrict__ sarr, float* __restrict__ sfac){
  int t = threadIdx.x;
  if (t < 24) sfac[t] = ALPHA_C * sqrtf(sarr[24+t] / sarr[t]);
}

__global__ void k_bias64(const double* __restrict__ mu64, float* __restrict__ bias2){
  int m2 = blockIdx.x, t = threadIdx.x;
  bias2[(size_t)m2*Cc + t] = (float)(0.6*mu64[(size_t)(24+m2)*Cc + t] + 0.4*mu64[(size_t)m2*Cc + t]);
}

__global__ __launch_bounds__(256) void k_transfer_d(const float* __restrict__ G, const float* __restrict__ cont,
                                                    const int* __restrict__ assign, const float* __restrict__ mu,
                                                    const float* __restrict__ bias2, float* __restrict__ out){
  __shared__ float As[16][132], Bs[16][132];
  __shared__ unsigned char al2[128];
  int m2 = blockIdx.z; int b = m2/Kk; int k = m2%Kk;
  const float* A = G + (size_t)m2*MSZ;
  const float* F = cont + (size_t)b*Cc*Nn;
  const float* muM = mu + (size_t)m2*Cc;
  int t = threadIdx.x;
  int i0 = blockIdx.x*128, j0 = blockIdx.y*128;
  int ar = t>>2, ac = (t&3)*4;
  int bk = t>>5, bj = (t&31)*4;
  int tx = t&15, ty = t>>4;
  if (t < 128) al2[t] = (unsigned char)assign[b*Nn + j0 + t];
  __syncthreads();
  float acc[8][8] = {};
  for (int kt=0; kt<Cc; kt+=16){
    float4 a0 = *(const float4*)(A + (size_t)(i0+ar)*Cc + kt + ac);
    float4 a1 = *(const float4*)(A + (size_t)(i0+ar+64)*Cc + kt + ac);
    float mb0 = muM[kt+bk], mb1 = muM[kt+bk+8];
    float4 b0 = *(const float4*)(F + (size_t)(kt+bk)*Nn + j0 + bj);
    float4 b1 = *(const float4*)(F + (size_t)(kt+bk+8)*Nn + j0 + bj);
    As[ac+0][ar]=a0.x; As[ac+1][ar]=a0.y; As[ac+2][ar]=a0.z; As[ac+3][ar]=a0.w;
    As[ac+0][ar+64]=a1.x; As[ac+1][ar+64]=a1.y; As[ac+2][ar+64]=a1.z; As[ac+3][ar+64]=a1.w;
    Bs[bk][bj+0]=b0.x-mb0; Bs[bk][bj+1]=b0.y-mb0; Bs[bk][bj+2]=b0.z-mb0; Bs[bk][bj+3]=b0.w-mb0;
    Bs[bk+8][bj+0]=b1.x-mb1; Bs[bk+8][bj+1]=b1.y-mb1; Bs[bk+8][bj+2]=b1.z-mb1; Bs[bk+8][bj+3]=b1.w-mb1;
    __syncthreads();
    #pragma unroll
    for (int kk=0; kk<16; kk++){
      float4 x0 = *(const float4*)&As[kk][ty*8];
      float4 x1 = *(const float4*)&As[kk][ty*8+4];
      float4 y0 = *(const float4*)&Bs[kk][tx*8];
      float4 y1 = *(const float4*)&Bs[kk][tx*8+4];
      float av[8] = {x0.x,x0.y,x0.z,x0.w,x1.x,x1.y,x1.z,x1.w};
      float bv[8] = {y0.x,y0.y,y0.z,y0.w,y1.x,y1.y,y1.z,y1.w};
      #pragma unroll
      for (int i=0;i<8;i++)
        #pragma unroll
        for (int j=0;j<8;j++) acc[i][j] = fmaf(av[i], bv[j], acc[i][j]);
    }
    __syncthreads();
  }
  #pragma unroll
  for (int j=0;j<8;j++){
    int lc2 = tx*8 + j;
    if (al2[lc2] != k) continue;
    int gj = j0 + lc2;
    #pragma unroll
    for (int i=0;i<8;i++){
      int gi = i0 + ty*8 + i;
      out[((size_t)b*Cc + gi)*Nn + gj] = acc[i][j] + bias2[(size_t)m2*Cc + gi];
    }
  }
}

extern "C" void kernel_launch(void* const* d_in, const int* in_sizes, int n_in,
                              void* d_out, int out_size, void* d_ws, size_t ws_size,
                              hipStream_t stream){
  const float* cont = (const float*)d_in[0];
  const float* sty  = (const float*)d_in[1];
  float* out = (float*)d_out;

  char* w = (char*)d_ws;
  size_t off = 0;
  auto alloc = [&](size_t bytes) -> void* {
    void* pp = (void*)(w + off);
    off = (off + bytes + 255) & ~(size_t)255;
    return pp;
  };
  float*  cent32 = (float*) alloc((size_t)NMAT*Cc*4);
  float*  csq32  = (float*) alloc((size_t)NMAT*4);
  float*  xsq32  = (float*) alloc((size_t)Pp*Nn*4);
  double* csum64 = (double*)alloc((size_t)NMAT*Cc*8);
  float*  cntf   = (float*) alloc((size_t)NMAT*4);
  double* mu64   = (double*)alloc((size_t)NMAT*Cc*8);
  float*  mu32   = (float*) alloc((size_t)NMAT*Cc*4);
  double* dvc64  = (double*)alloc((size_t)NMAT*8);
  float*  sarr   = (float*) alloc((size_t)NMAT*4);
  float*  sfac   = (float*) alloc((size_t)24*4);
  float*  bias2  = (float*) alloc((size_t)24*Cc*4);
  int*    assign = (int*)   alloc((size_t)Pp*Nn*4);
  float*  G      = (float*) alloc((size_t)24*MSZ*4);
  float*  nsResC = (float*) alloc((size_t)24*MSZ*4);
  float*  styY6  = (float*) alloc((size_t)NSB6*MSZ*4);
  double* cov64  = (double*)alloc((size_t)NMAT*MSZ*8);
  (void)ws_size; (void)in_sizes; (void)n_in; (void)out_size;

  // d_out doubles as fp64 NS scratch (4 x 6 x 2 MiB = 48 MiB); transfer rewrites all.
  double* douts64 = (double*)d_out;
  double* W0 = douts64;
  double* W1 = douts64 + (size_t)1*NSB6*MSZ;
  double* W2 = douts64 + (size_t)2*NSB6*MSZ;
  double* W3 = douts64 + (size_t)3*NSB6*MSZ;

  // ---- ideal-fp32 k-means (exact arithmetic, fp32 roundings at reference boundaries) ----
  k_init_cent32<<<NMAT, Cc, 0, stream>>>(cont, sty, cent32);
  k_xsq32<<<dim3(Pp,16), 256, 0, stream>>>(cont, sty, xsq32);
  for (int it=0; it<10; ++it){
    k_csq32<<<1, 64, 0, stream>>>(cent32, csq32);
    k_assign_i32<<<dim3(Pp,16), 256, 0, stream>>>(cont, sty, cent32, csq32, xsq32, assign);
    k_update64<<<dim3(Pp,8), 256, 0, stream>>>(cont, sty, assign, csum64, cntf);
    k_centupd32<<<NMAT, Cc, 0, stream>>>(csum64, cntf, cent32);
  }
  k_csq32<<<1, 64, 0, stream>>>(cent32, csq32);
  k_assign_i32<<<dim3(Pp,16), 256, 0, stream>>>(cont, sty, cent32, csq32, xsq32, assign);

  // ---- fp64 stats (verified) ----
  k_update64<<<dim3(Pp,8), 256, 0, stream>>>(cont, sty, assign, csum64, cntf);
  k_mu64<<<NMAT, Cc, 0, stream>>>(csum64, cntf, mu64, mu32, dvc64);
  k_covd64<<<dim3(8,8,NMAT), 256, 0, stream>>>(cont, sty, assign, mu64, dvc64, cov64);
  k_power64<<<NMAT, 256, 0, stream>>>(cov64, sarr);
  k_sfac<<<1, 32, 0, stream>>>(sarr, sfac);
  k_bias64<<<24, Cc, 0, stream>>>(mu64, bias2);

  // ---- fp64 coupled Newton-Schulz, 26 iters, 8 batches of 6 ----
  for (int bt=0; bt<NMAT/NSB6; ++bt){
    int m0 = bt*NSB6;
    k_scale_init64<<<dim3(NSB6,32), 256, 0, stream>>>(cov64, sarr, W0, W1, m0);
    double *Y=W0, *Z=W1, *T=W2, *S=W3;
    for (int it=0; it<NS64_ITERS; ++it){
      gemm64d<2><<<dim3(8,8,NSB6), 256, 0, stream>>>(Z, Y, T);
      gemm64d<0><<<dim3(8,8,NSB6), 256, 0, stream>>>(Y, T, S);
      gemm64d<0><<<dim3(8,8,NSB6), 256, 0, stream>>>(T, Z, Y);
      double* oy = Y; double* oz = Z;
      Y = S; Z = oy; S = oz;
    }
    if (m0 < 24){
      k_keepC<<<dim3(NSB6,128), 256, 0, stream>>>(Z, nsResC, m0);
    } else {
      k_keepS<<<dim3(NSB6,128), 256, 0, stream>>>(Y, styY6);
      int moff = m0 - 24;
      gemm128<2><<<dim3(4,4,NSB6), 256, 0, stream>>>(styY6, nsResC + (size_t)moff*MSZ,
                                                     G + (size_t)moff*MSZ, sfac + moff);
    }
  }

  // ---- apply transform + blend, direct masked write ----
  k_transfer_d<<<dim3(4,32,24), 256, 0, stream>>>(G, cont, assign, mu32, bias2, out);
}

// Round 14
// 25124.663 us; speedup vs baseline: 2.1186x; 2.1186x over previous
//
#include <hip/hip_runtime.h>
#include <math.h>
#include <cstddef>

#define Bn 8
#define Cc 512
#define Nn 4096
#define Kk 3
#define Pp 16
#define NMAT 48
#define MSZ (Cc*Cc)
#define ALPHA_C 0.6f
#define BETA_C 0.4f
#define GAMMA_C 0.1
#define POW_ITERS 8
#define NS32_ITERS 22
#define NSB16 16

__device__ __forceinline__ const float* Fbase(const float* cont, const float* sty, int p){
  return (p < Bn) ? (cont + (size_t)p*Cc*Nn) : (sty + (size_t)(p-Bn)*Cc*Nn);
}

// ===== ideal-fp32 k-means (round-13 verified: DO NOT TOUCH) =====
__global__ void k_init_cent32(const float* __restrict__ cont, const float* __restrict__ sty,
                              float* __restrict__ cent32){
  int m = blockIdx.x; int p = m/Kk, k = m%Kk;
  const int ninit[3] = {0, 2047, 4095};
  const float* F = Fbase(cont, sty, p);
  int c = threadIdx.x;
  cent32[(size_t)m*Cc + c] = F[(size_t)c*Nn + ninit[k]];
}

__global__ __launch_bounds__(256) void k_xsq32(const float* __restrict__ cont, const float* __restrict__ sty,
                                               float* __restrict__ xsq32){
  int p = blockIdx.x;
  int n = blockIdx.y*256 + threadIdx.x;
  const float* F = Fbase(cont, sty, p);
  double s = 0.0;
  for (int c=0; c<Cc; c++){ double v = (double)F[(size_t)c*Nn + n]; s += v*v; }
  xsq32[p*Nn + n] = (float)s;
}

__global__ void k_csq32(const float* __restrict__ cent32, float* __restrict__ csq32){
  int m = threadIdx.x;
  if (m >= NMAT) return;
  const float* c = cent32 + (size_t)m*Cc;
  double s = 0.0;
  for (int i=0;i<Cc;i++){ double v = (double)c[i]; s += v*v; }
  csq32[m] = (float)s;
}

__global__ __launch_bounds__(256) void k_assign_i32(const float* __restrict__ cont, const float* __restrict__ sty,
                                                    const float* __restrict__ cent32, const float* __restrict__ csq32,
                                                    const float* __restrict__ xsq32, int* __restrict__ assign){
  __shared__ float cl[Kk][Cc];
  int p = blockIdx.x, t = threadIdx.x;
  const float* F = Fbase(cont, sty, p);
  for (int i=t; i<Kk*Cc; i+=256) ((float*)cl)[i] = cent32[(size_t)p*Kk*Cc + i];
  __syncthreads();
  float cs0 = csq32[p*Kk+0], cs1 = csq32[p*Kk+1], cs2 = csq32[p*Kk+2];
  int n = blockIdx.y*256 + t;
  const float* col = F + n;
  double d0=0.0, d1=0.0, d2=0.0;
  for (int c=0; c<Cc; c++){
    double f = (double)col[(size_t)c*Nn];
    d0 += f*(double)cl[0][c];
    d1 += f*(double)cl[1][c];
    d2 += f*(double)cl[2][c];
  }
  float f0 = (float)d0, f1 = (float)d1, f2 = (float)d2;
  float xs = xsq32[p*Nn + n];
  float D0, D1, D2;
  {
    #pragma clang fp contract(off)
    D0 = (xs - 2.f*f0) + cs0;
    D1 = (xs - 2.f*f1) + cs1;
    D2 = (xs - 2.f*f2) + cs2;
  }
  int a = 0; float best = D0;
  if (D1 < best){ best = D1; a = 1; }
  if (D2 < best){ best = D2; a = 2; }
  assign[p*Nn + n] = a;
}

__global__ __launch_bounds__(256) void k_update64(const float* __restrict__ cont, const float* __restrict__ sty,
                                                  const int* __restrict__ assign,
                                                  double* __restrict__ csum, float* __restrict__ cntf){
  __shared__ unsigned char al[Nn];
  __shared__ int ri[256];
  int p = blockIdx.x, cg = blockIdx.y, t = threadIdx.x;
  const float* F = Fbase(cont, sty, p);
  for (int i=t; i<Nn; i+=256) al[i] = (unsigned char)assign[p*Nn+i];
  __syncthreads();
  int wave = t>>6, lane = t&63;
  for (int rr=0; rr<16; rr++){
    int r = cg*64 + wave*16 + rr;
    const float* row = F + (size_t)r*Nn;
    double s0=0.0,s1=0.0,s2=0.0;
    for (int n=lane; n<Nn; n+=64){
      double f = (double)row[n]; int a = al[n];
      s0 += (a==0)?f:0.0; s1 += (a==1)?f:0.0; s2 += (a==2)?f:0.0;
    }
    for (int off=32; off>0; off>>=1){
      s0 += __shfl_xor(s0,off); s1 += __shfl_xor(s1,off); s2 += __shfl_xor(s2,off);
    }
    if (lane==0){
      csum[((size_t)p*Kk+0)*Cc + r] = s0;
      csum[((size_t)p*Kk+1)*Cc + r] = s1;
      csum[((size_t)p*Kk+2)*Cc + r] = s2;
    }
  }
  if (cg==0){
    int c0=0,c1=0,c2=0;
    for (int n=t;n<Nn;n+=256){ int a=al[n]; c0+=(a==0); c1+=(a==1); c2+=(a==2); }
    for (int k=0;k<3;k++){
      int v = (k==0)?c0:((k==1)?c1:c2);
      ri[t] = v; __syncthreads();
      for (int off=128; off>0; off>>=1){ if(t<off) ri[t]+=ri[t+off]; __syncthreads(); }
      if (t==0) cntf[p*Kk+k] = (float)ri[0];
      __syncthreads();
    }
  }
}

__global__ void k_centupd32(const double* __restrict__ csum, const float* __restrict__ cntf,
                            float* __restrict__ cent32){
  int m = blockIdx.x, c = threadIdx.x;
  float n = cntf[m];
  if (n > 0.f){
    float s32 = (float)csum[(size_t)m*Cc + c];
    cent32[(size_t)m*Cc + c] = s32 / fmaxf(n, 1.f);
  }
}

__global__ void k_mu64(const double* __restrict__ csum, const float* __restrict__ cntf,
                       double* __restrict__ mu64, float* __restrict__ mu32, double* __restrict__ dvc){
  int m = blockIdx.x, t = threadIdx.x;
  double n = fmax((double)cntf[m], 1.0);
  double v = csum[(size_t)m*Cc+t] / n;
  mu64[(size_t)m*Cc+t] = v;
  mu32[(size_t)m*Cc+t] = (float)v;
  if (t==0) dvc[m] = 1.0 / fmax(n-1.0, 1.0);
}

// cov: fp64 accumulation, fp32 store (round-12 verified output-invisible)
__global__ __launch_bounds__(256) void k_covd32(const float* __restrict__ cont, const float* __restrict__ sty,
                                                const int* __restrict__ assign, const double* __restrict__ mu,
                                                const double* __restrict__ dvc, float* __restrict__ A32){
  __shared__ double As[16][66], Bs[16][66];
  __shared__ unsigned char al[Nn];
  int m = blockIdx.z; int p = m/Kk; int k = m%Kk;
  const float* F = Fbase(cont, sty, p);
  int t = threadIdx.x;
  for (int i=t; i<Nn; i+=256) al[i] = (unsigned char)assign[p*Nn+i];
  int i0 = blockIdx.x*64, j0 = blockIdx.y*64;
  int lr = t>>2, lc = (t&3)*4;
  int ty = t>>4, tx = t&15;
  const double* muM = mu + (size_t)m*Cc;
  double muA = muM[i0+lr];
  double muB = muM[j0+lr];
  __syncthreads();
  double acc[4][4] = {};
  for (int kt=0; kt<Nn; kt+=16){
    float4 av = *(const float4*)(F + (size_t)(i0+lr)*Nn + kt + lc);
    float4 bv = *(const float4*)(F + (size_t)(j0+lr)*Nn + kt + lc);
    double mk[4];
    #pragma unroll
    for (int u=0;u<4;u++) mk[u] = (al[kt+lc+u]==k) ? 1.0 : 0.0;
    As[lc+0][lr] = mk[0]*((double)av.x-muA);
    As[lc+1][lr] = mk[1]*((double)av.y-muA);
    As[lc+2][lr] = mk[2]*((double)av.z-muA);
    As[lc+3][lr] = mk[3]*((double)av.w-muA);
    Bs[lc+0][lr] = (double)bv.x-muB;
    Bs[lc+1][lr] = (double)bv.y-muB;
    Bs[lc+2][lr] = (double)bv.z-muB;
    Bs[lc+3][lr] = (double)bv.w-muB;
    __syncthreads();
    #pragma unroll
    for (int kk=0; kk<16; kk++){
      double aa[4], bb[4];
      #pragma unroll
      for (int i=0;i<4;i++) aa[i] = As[kk][ty*4+i];
      #pragma unroll
      for (int j=0;j<4;j++) bb[j] = Bs[kk][tx*4+j];
      #pragma unroll
      for (int i=0;i<4;i++)
        #pragma unroll
        for (int j=0;j<4;j++) acc[i][j] = fma(aa[i], bb[j], acc[i][j]);
    }
    __syncthreads();
  }
  double dv = dvc[m];
  #pragma unroll
  for (int i=0;i<4;i++){
    int gi = i0 + ty*4 + i;
    #pragma unroll
    for (int j=0;j<4;j++){
      int gj = j0 + tx*4 + j;
      double v = acc[i][j]*dv;
      if (gi==gj) v += GAMMA_C;
      A32[(size_t)m*MSZ + (size_t)gi*Cc + gj] = (float)v;
    }
  }
}

// power iteration on fp32 cov (fp64 accum) -> s = 1.3*lambda_max
__global__ __launch_bounds__(256) void k_power32(const float* __restrict__ A32, float* __restrict__ sarr){
  __shared__ double v[Cc], w[Cc], red[256];
  int m = blockIdx.x, t = threadIdx.x;
  const float* A = A32 + (size_t)m*MSZ;
  for (int i=t;i<Cc;i+=256) v[i] = 1.0;
  __syncthreads();
  int wave = t>>6, lane = t&63;
  for (int it=0; it<POW_ITERS+1; it++){
    for (int r = wave*128; r < wave*128+128; r++){
      const float* row = A + (size_t)r*Cc;
      double pa = 0.0;
      for (int j=lane; j<Cc; j+=64) pa += (double)row[j]*v[j];
      for (int off=32; off>0; off>>=1) pa += __shfl_xor(pa, off);
      if (lane==0) w[r] = pa;
    }
    __syncthreads();
    if (it < POW_ITERS){
      double nn = 0.0;
      for (int i=t;i<Cc;i+=256) nn += w[i]*w[i];
      red[t]=nn; __syncthreads();
      for (int off=128;off>0;off>>=1){ if(t<off) red[t]+=red[t+off]; __syncthreads(); }
      double inv = rsqrt(fmax(red[0], 1e-300));
      __syncthreads();
      for (int i=t;i<Cc;i+=256) v[i] = w[i]*inv;
      __syncthreads();
    }
  }
  double rr = 0.0;
  for (int i=t;i<Cc;i+=256) rr += v[i]*w[i];
  red[t]=rr; __syncthreads();
  for (int off=128;off>0;off>>=1){ if(t<off) red[t]+=red[t+off]; __syncthreads(); }
  if (t==0) sarr[m] = (float)(1.3*red[0] + 1e-6);
}

// batched fp32: Y[i] = cov32[m0+i]/s, Z[i] = I
__global__ __launch_bounds__(256) void k_scale_init32(const float* __restrict__ cov32, const float* __restrict__ sarr,
                                                      float* __restrict__ Y, float* __restrict__ Z, int m0){
  int i = blockIdx.x, t = threadIdx.x;
  float rs = 1.f / sarr[m0+i];
  const float* src = cov32 + (size_t)(m0+i)*MSZ;
  size_t base = (size_t)i*MSZ;
  int j0 = blockIdx.y*8192;
  for (int j = j0 + t; j < j0 + 8192; j += 256){
    Y[base+j] = src[j]*rs;
    int r = j>>9, c = j&511;
    Z[base+j] = (r==c) ? 1.f : 0.f;
  }
}

// per-matrix keep: content -> nsResC (Z), style -> styAll (Y)
__global__ __launch_bounds__(256) void k_keep32(const float* __restrict__ Yb, const float* __restrict__ Zb,
                                                float* __restrict__ nsResC, float* __restrict__ styAll, int m0){
  int i = blockIdx.x, t = threadIdx.x;
  int mm = m0 + i;
  const float* src = (mm < 24) ? (Zb + (size_t)i*MSZ) : (Yb + (size_t)i*MSZ);
  float* dst = (mm < 24) ? (nsResC + (size_t)mm*MSZ) : (styAll + (size_t)(mm-24)*MSZ);
  int j0 = blockIdx.y*2048;
  for (int j = j0 + t; j < j0 + 2048; j += 256) dst[j] = src[j];
}

// fp32 batched GEMM 128x128, 8x8 micro.
// MODE 0: C=A@B   MODE 2: C = sfac[m]*(A@B)+0.4I   MODE 3: C = 1.5I-0.5*(A@B)
template<int MODE>
__global__ __launch_bounds__(256) void gemm128(const float* __restrict__ Ab, const float* __restrict__ Bb,
                                               float* __restrict__ Cb, const float* __restrict__ sfac){
  __shared__ float As[16][132], Bs[16][132];
  int m = blockIdx.z;
  const float* A = Ab + (size_t)m*MSZ;
  const float* Bm = Bb + (size_t)m*MSZ;
  float* Cm = Cb + (size_t)m*MSZ;
  int t = threadIdx.x;
  int tx = t&15, ty = t>>4;
  int i0 = blockIdx.x*128, j0 = blockIdx.y*128;
  int ar = t>>2, ac = (t&3)*4;
  int bk = t>>5, bj = (t&31)*4;
  float acc[8][8] = {};
  for (int kt=0; kt<Cc; kt+=16){
    float4 a0 = *(const float4*)(A + (size_t)(i0+ar)*Cc + kt + ac);
    float4 a1 = *(const float4*)(A + (size_t)(i0+ar+64)*Cc + kt + ac);
    float4 b0 = *(const float4*)(Bm + (size_t)(kt+bk)*Cc + j0 + bj);
    float4 b1 = *(const float4*)(Bm + (size_t)(kt+bk+8)*Cc + j0 + bj);
    As[ac+0][ar]=a0.x; As[ac+1][ar]=a0.y; As[ac+2][ar]=a0.z; As[ac+3][ar]=a0.w;
    As[ac+0][ar+64]=a1.x; As[ac+1][ar+64]=a1.y; As[ac+2][ar+64]=a1.z; As[ac+3][ar+64]=a1.w;
    *(float4*)&Bs[bk][bj] = b0;
    *(float4*)&Bs[bk+8][bj] = b1;
    __syncthreads();
    #pragma unroll
    for (int kk=0; kk<16; kk++){
      float4 x0 = *(const float4*)&As[kk][ty*8];
      float4 x1 = *(const float4*)&As[kk][ty*8+4];
      float4 y0 = *(const float4*)&Bs[kk][tx*8];
      float4 y1 = *(const float4*)&Bs[kk][tx*8+4];
      float av[8] = {x0.x,x0.y,x0.z,x0.w,x1.x,x1.y,x1.z,x1.w};
      float bv[8] = {y0.x,y0.y,y0.z,y0.w,y1.x,y1.y,y1.z,y1.w};
      #pragma unroll
      for (int i=0;i<8;i++)
        #pragma unroll
        for (int j=0;j<8;j++) acc[i][j] = fmaf(av[i], bv[j], acc[i][j]);
    }
    __syncthreads();
  }
  float sf = (MODE==2) ? sfac[m] : 0.f;
  #pragma unroll
  for (int i=0;i<8;i++){
    int gi = i0 + ty*8 + i;
    #pragma unroll
    for (int j=0;j<8;j++){
      int gj = j0 + tx*8 + j;
      float pv = acc[i][j];
      float v;
      if (MODE==2)      v = sf*pv + ((gi==gj)?BETA_C:0.f);
      else if (MODE==3) v = -0.5f*pv + ((gi==gj)?1.5f:0.f);
      else              v = pv;
      Cm[(size_t)gi*Cc + gj] = v;
    }
  }
}

__global__ void k_sfac(const float* __restrict__ sarr, float* __restrict__ sfac){
  int t = threadIdx.x;
  if (t < 24) sfac[t] = ALPHA_C * sqrtf(sarr[24+t] / sarr[t]);
}

__global__ void k_bias64(const double* __restrict__ mu64, float* __restrict__ bias2){
  int m2 = blockIdx.x, t = threadIdx.x;
  bias2[(size_t)m2*Cc + t] = (float)(0.6*mu64[(size_t)(24+m2)*Cc + t] + 0.4*mu64[(size_t)m2*Cc + t]);
}

__global__ __launch_bounds__(256) void k_transfer_d(const float* __restrict__ G, const float* __restrict__ cont,
                                                    const int* __restrict__ assign, const float* __restrict__ mu,
                                                    const float* __restrict__ bias2, float* __restrict__ out){
  __shared__ float As[16][132], Bs[16][132];
  __shared__ unsigned char al2[128];
  int m2 = blockIdx.z; int b = m2/Kk; int k = m2%Kk;
  const float* A = G + (size_t)m2*MSZ;
  const float* F = cont + (size_t)b*Cc*Nn;
  const float* muM = mu + (size_t)m2*Cc;
  int t = threadIdx.x;
  int i0 = blockIdx.x*128, j0 = blockIdx.y*128;
  int ar = t>>2, ac = (t&3)*4;
  int bk = t>>5, bj = (t&31)*4;
  int tx = t&15, ty = t>>4;
  if (t < 128) al2[t] = (unsigned char)assign[b*Nn + j0 + t];
  __syncthreads();
  float acc[8][8] = {};
  for (int kt=0; kt<Cc; kt+=16){
    float4 a0 = *(const float4*)(A + (size_t)(i0+ar)*Cc + kt + ac);
    float4 a1 = *(const float4*)(A + (size_t)(i0+ar+64)*Cc + kt + ac);
    float mb0 = muM[kt+bk], mb1 = muM[kt+bk+8];
    float4 b0 = *(const float4*)(F + (size_t)(kt+bk)*Nn + j0 + bj);
    float4 b1 = *(const float4*)(F + (size_t)(kt+bk+8)*Nn + j0 + bj);
    As[ac+0][ar]=a0.x; As[ac+1][ar]=a0.y; As[ac+2][ar]=a0.z; As[ac+3][ar]=a0.w;
    As[ac+0][ar+64]=a1.x; As[ac+1][ar+64]=a1.y; As[ac+2][ar+64]=a1.z; As[ac+3][ar+64]=a1.w;
    Bs[bk][bj+0]=b0.x-mb0; Bs[bk][bj+1]=b0.y-mb0; Bs[bk][bj+2]=b0.z-mb0; Bs[bk][bj+3]=b0.w-mb0;
    Bs[bk+8][bj+0]=b1.x-mb1; Bs[bk+8][bj+1]=b1.y-mb1; Bs[bk+8][bj+2]=b1.z-mb1; Bs[bk+8][bj+3]=b1.w-mb1;
    __syncthreads();
    #pragma unroll
    for (int kk=0; kk<16; kk++){
      float4 x0 = *(const float4*)&As[kk][ty*8];
      float4 x1 = *(const float4*)&As[kk][ty*8+4];
      float4 y0 = *(const float4*)&Bs[kk][tx*8];
      float4 y1 = *(const float4*)&Bs[kk][tx*8+4];
      float av[8] = {x0.x,x0.y,x0.z,x0.w,x1.x,x1.y,x1.z,x1.w};
      float bv[8] = {y0.x,y0.y,y0.z,y0.w,y1.x,y1.y,y1.z,y1.w};
      #pragma unroll
      for (int i=0;i<8;i++)
        #pragma unroll
        for (int j=0;j<8;j++) acc[i][j] = fmaf(av[i], bv[j], acc[i][j]);
    }
    __syncthreads();
  }
  #pragma unroll
  for (int j=0;j<8;j++){
    int lc2 = tx*8 + j;
    if (al2[lc2] != k) continue;
    int gj = j0 + lc2;
    #pragma unroll
    for (int i=0;i<8;i++){
      int gi = i0 + ty*8 + i;
      out[((size_t)b*Cc + gi)*Nn + gj] = acc[i][j] + bias2[(size_t)m2*Cc + gi];
    }
  }
}

extern "C" void kernel_launch(void* const* d_in, const int* in_sizes, int n_in,
                              void* d_out, int out_size, void* d_ws, size_t ws_size,
                              hipStream_t stream){
  const float* cont = (const float*)d_in[0];
  const float* sty  = (const float*)d_in[1];
  float* out = (float*)d_out;

  char* w = (char*)d_ws;
  size_t off = 0;
  auto alloc = [&](size_t bytes) -> void* {
    void* pp = (void*)(w + off);
    off = (off + bytes + 255) & ~(size_t)255;
    return pp;
  };
  float*  cent32 = (float*) alloc((size_t)NMAT*Cc*4);
  float*  csq32  = (float*) alloc((size_t)NMAT*4);
  float*  xsq32  = (float*) alloc((size_t)Pp*Nn*4);
  double* csum64 = (double*)alloc((size_t)NMAT*Cc*8);
  float*  cntf   = (float*) alloc((size_t)NMAT*4);
  double* mu64   = (double*)alloc((size_t)NMAT*Cc*8);
  float*  mu32   = (float*) alloc((size_t)NMAT*Cc*4);
  double* dvc64  = (double*)alloc((size_t)NMAT*8);
  float*  sarr   = (float*) alloc((size_t)NMAT*4);
  float*  sfac   = (float*) alloc((size_t)24*4);
  float*  bias2  = (float*) alloc((size_t)24*Cc*4);
  int*    assign = (int*)   alloc((size_t)Pp*Nn*4);
  float*  G      = (float*) alloc((size_t)24*MSZ*4);   // 25 MB
  float*  nsResC = (float*) alloc((size_t)24*MSZ*4);   // 25 MB (content Z)
  float*  styAll = (float*) alloc((size_t)24*MSZ*4);   // 25 MB (style Y)
  float*  cov32  = (float*) alloc((size_t)NMAT*MSZ*4); // 50 MB
  (void)ws_size; (void)in_sizes; (void)n_in; (void)out_size;

  // d_out = 64 MiB doubles as fp32 NS scratch: 4 buffers x 16 mats x 1 MiB.
  float* douts = (float*)d_out;
  float* W0 = douts;
  float* W1 = douts + (size_t)1*NSB16*MSZ;
  float* W2 = douts + (size_t)2*NSB16*MSZ;
  float* W3 = douts + (size_t)3*NSB16*MSZ;

  // ---- ideal-fp32 k-means ----
  k_init_cent32<<<NMAT, Cc, 0, stream>>>(cont, sty, cent32);
  k_xsq32<<<dim3(Pp,16), 256, 0, stream>>>(cont, sty, xsq32);
  for (int it=0; it<10; ++it){
    k_csq32<<<1, 64, 0, stream>>>(cent32, csq32);
    k_assign_i32<<<dim3(Pp,16), 256, 0, stream>>>(cont, sty, cent32, csq32, xsq32, assign);
    k_update64<<<dim3(Pp,8), 256, 0, stream>>>(cont, sty, assign, csum64, cntf);
    k_centupd32<<<NMAT, Cc, 0, stream>>>(csum64, cntf, cent32);
  }
  k_csq32<<<1, 64, 0, stream>>>(cent32, csq32);
  k_assign_i32<<<dim3(Pp,16), 256, 0, stream>>>(cont, sty, cent32, csq32, xsq32, assign);

  // ---- stats ----
  k_update64<<<dim3(Pp,8), 256, 0, stream>>>(cont, sty, assign, csum64, cntf);
  k_mu64<<<NMAT, Cc, 0, stream>>>(csum64, cntf, mu64, mu32, dvc64);
  k_covd32<<<dim3(8,8,NMAT), 256, 0, stream>>>(cont, sty, assign, mu64, dvc64, cov32);
  k_power32<<<NMAT, 256, 0, stream>>>(cov32, sarr);
  k_sfac<<<1, 32, 0, stream>>>(sarr, sfac);
  k_bias64<<<24, Cc, 0, stream>>>(mu64, bias2);

  // ---- fp32 coupled Newton-Schulz, 22 iters, 3 batches of 16 ----
  for (int bt=0; bt<NMAT/NSB16; ++bt){
    int m0 = bt*NSB16;
    k_scale_init32<<<dim3(NSB16,32), 256, 0, stream>>>(cov32, sarr, W0, W1, m0);
    float *Y=W0, *Z=W1, *T=W2, *S=W3;
    for (int it=0; it<NS32_ITERS; ++it){
      gemm128<3><<<dim3(4,4,NSB16), 256, 0, stream>>>(Z, Y, T, nullptr);  // T = 1.5I - 0.5 Z@Y
      gemm128<0><<<dim3(4,4,NSB16), 256, 0, stream>>>(Y, T, S, nullptr);  // S = Y@T (new Y)
      gemm128<0><<<dim3(4,4,NSB16), 256, 0, stream>>>(T, Z, Y, nullptr);  // old-Y buf <- T@Z (new Z)
      float* oy = Y; float* oz = Z;
      Y = S; Z = oy; S = oz;
    }
    k_keep32<<<dim3(NSB16,128), 256, 0, stream>>>(Y, Z, nsResC, styAll, m0);
  }

  // ---- G = sfac*(Y_style @ Z_content) + 0.4 I ----
  gemm128<2><<<dim3(4,4,24), 256, 0, stream>>>(styAll, nsResC, G, sfac);

  // ---- apply transform + blend, direct masked write ----
  k_transfer_d<<<dim3(4,32,24), 256, 0, stream>>>(G, cont, assign, mu32, bias2, out);
}

// Round 16
// 19919.141 us; speedup vs baseline: 2.6722x; 1.2613x over previous
//
#include <hip/hip_runtime.h>
#include <math.h>
#include <cstddef>

#define Bn 8
#define Cc 512
#define Nn 4096
#define Kk 3
#define Pp 16
#define NMAT 48
#define MSZ (Cc*Cc)
#define ALPHA_C 0.6f
#define BETA_C 0.4f
#define GAMMA_C 0.1
#define POW_ITERS 8
#define NSB_ITERS 18
#define NSB16 16

using s8v = __attribute__((ext_vector_type(8))) short;
using f4v = __attribute__((ext_vector_type(4))) float;

__device__ __forceinline__ float b2fs(short u){
  union { unsigned i; float f; } x; x.i = ((unsigned)(unsigned short)u) << 16; return x.f;
}
__device__ __forceinline__ short f2bs(float f){
  unsigned u = __float_as_uint(f);
  unsigned r = (u + 0x7FFF + ((u >> 16) & 1)) >> 16;
  return (short)r;
}

__device__ __forceinline__ const float* Fbase(const float* cont, const float* sty, int p){
  return (p < Bn) ? (cont + (size_t)p*Cc*Nn) : (sty + (size_t)(p-Bn)*Cc*Nn);
}

// ===== ideal-fp32 k-means (round-13 verified: DO NOT TOUCH) =====
__global__ void k_init_cent32(const float* __restrict__ cont, const float* __restrict__ sty,
                              float* __restrict__ cent32){
  int m = blockIdx.x; int p = m/Kk, k = m%Kk;
  const int ninit[3] = {0, 2047, 4095};
  const float* F = Fbase(cont, sty, p);
  int c = threadIdx.x;
  cent32[(size_t)m*Cc + c] = F[(size_t)c*Nn + ninit[k]];
}

__global__ __launch_bounds__(256) void k_xsq32(const float* __restrict__ cont, const float* __restrict__ sty,
                                               float* __restrict__ xsq32){
  int p = blockIdx.x;
  int n = blockIdx.y*256 + threadIdx.x;
  const float* F = Fbase(cont, sty, p);
  double s = 0.0;
  for (int c=0; c<Cc; c++){ double v = (double)F[(size_t)c*Nn + n]; s += v*v; }
  xsq32[p*Nn + n] = (float)s;
}

__global__ void k_csq32(const float* __restrict__ cent32, float* __restrict__ csq32){
  int m = threadIdx.x;
  if (m >= NMAT) return;
  const float* c = cent32 + (size_t)m*Cc;
  double s = 0.0;
  for (int i=0;i<Cc;i++){ double v = (double)c[i]; s += v*v; }
  csq32[m] = (float)s;
}

__global__ __launch_bounds__(256) void k_assign_i32(const float* __restrict__ cont, const float* __restrict__ sty,
                                                    const float* __restrict__ cent32, const float* __restrict__ csq32,
                                                    const float* __restrict__ xsq32, int* __restrict__ assign){
  __shared__ float cl[Kk][Cc];
  int p = blockIdx.x, t = threadIdx.x;
  const float* F = Fbase(cont, sty, p);
  for (int i=t; i<Kk*Cc; i+=256) ((float*)cl)[i] = cent32[(size_t)p*Kk*Cc + i];
  __syncthreads();
  float cs0 = csq32[p*Kk+0], cs1 = csq32[p*Kk+1], cs2 = csq32[p*Kk+2];
  int n = blockIdx.y*256 + t;
  const float* col = F + n;
  double d0=0.0, d1=0.0, d2=0.0;
  for (int c=0; c<Cc; c++){
    double f = (double)col[(size_t)c*Nn];
    d0 += f*(double)cl[0][c];
    d1 += f*(double)cl[1][c];
    d2 += f*(double)cl[2][c];
  }
  float f0 = (float)d0, f1 = (float)d1, f2 = (float)d2;
  float xs = xsq32[p*Nn + n];
  float D0, D1, D2;
  {
    #pragma clang fp contract(off)
    D0 = (xs - 2.f*f0) + cs0;
    D1 = (xs - 2.f*f1) + cs1;
    D2 = (xs - 2.f*f2) + cs2;
  }
  int a = 0; float best = D0;
  if (D1 < best){ best = D1; a = 1; }
  if (D2 < best){ best = D2; a = 2; }
  assign[p*Nn + n] = a;
}

__global__ __launch_bounds__(256) void k_update64(const float* __restrict__ cont, const float* __restrict__ sty,
                                                  const int* __restrict__ assign,
                                                  double* __restrict__ csum, float* __restrict__ cntf){
  __shared__ unsigned char al[Nn];
  __shared__ int ri[256];
  int p = blockIdx.x, cg = blockIdx.y, t = threadIdx.x;
  const float* F = Fbase(cont, sty, p);
  for (int i=t; i<Nn; i+=256) al[i] = (unsigned char)assign[p*Nn+i];
  __syncthreads();
  int wave = t>>6, lane = t&63;
  for (int rr=0; rr<16; rr++){
    int r = cg*64 + wave*16 + rr;
    const float* row = F + (size_t)r*Nn;
    double s0=0.0,s1=0.0,s2=0.0;
    for (int n=lane; n<Nn; n+=64){
      double f = (double)row[n]; int a = al[n];
      s0 += (a==0)?f:0.0; s1 += (a==1)?f:0.0; s2 += (a==2)?f:0.0;
    }
    for (int off=32; off>0; off>>=1){
      s0 += __shfl_xor(s0,off); s1 += __shfl_xor(s1,off); s2 += __shfl_xor(s2,off);
    }
    if (lane==0){
      csum[((size_t)p*Kk+0)*Cc + r] = s0;
      csum[((size_t)p*Kk+1)*Cc + r] = s1;
      csum[((size_t)p*Kk+2)*Cc + r] = s2;
    }
  }
  if (cg==0){
    int c0=0,c1=0,c2=0;
    for (int n=t;n<Nn;n+=256){ int a=al[n]; c0+=(a==0); c1+=(a==1); c2+=(a==2); }
    for (int k=0;k<3;k++){
      int v = (k==0)?c0:((k==1)?c1:c2);
      ri[t] = v; __syncthreads();
      for (int off=128; off>0; off>>=1){ if(t<off) ri[t]+=ri[t+off]; __syncthreads(); }
      if (t==0) cntf[p*Kk+k] = (float)ri[0];
      __syncthreads();
    }
  }
}

__global__ void k_centupd32(const double* __restrict__ csum, const float* __restrict__ cntf,
                            float* __restrict__ cent32){
  int m = blockIdx.x, c = threadIdx.x;
  float n = cntf[m];
  if (n > 0.f){
    float s32 = (float)csum[(size_t)m*Cc + c];
    cent32[(size_t)m*Cc + c] = s32 / fmaxf(n, 1.f);
  }
}

__global__ void k_mu64(const double* __restrict__ csum, const float* __restrict__ cntf,
                       double* __restrict__ mu64, float* __restrict__ mu32, double* __restrict__ dvc){
  int m = blockIdx.x, t = threadIdx.x;
  double n = fmax((double)cntf[m], 1.0);
  double v = csum[(size_t)m*Cc+t] / n;
  mu64[(size_t)m*Cc+t] = v;
  mu32[(size_t)m*Cc+t] = (float)v;
  if (t==0) dvc[m] = 1.0 / fmax(n-1.0, 1.0);
}

// cov: fp64 accumulation, fp32 store
__global__ __launch_bounds__(256) void k_covd32(const float* __restrict__ cont, const float* __restrict__ sty,
                                                const int* __restrict__ assign, const double* __restrict__ mu,
                                                const double* __restrict__ dvc, float* __restrict__ A32){
  __shared__ double As[16][66], Bs[16][66];
  __shared__ unsigned char al[Nn];
  int m = blockIdx.z; int p = m/Kk; int k = m%Kk;
  const float* F = Fbase(cont, sty, p);
  int t = threadIdx.x;
  for (int i=t; i<Nn; i+=256) al[i] = (unsigned char)assign[p*Nn+i];
  int i0 = blockIdx.x*64, j0 = blockIdx.y*64;
  int lr = t>>2, lc = (t&3)*4;
  int ty = t>>4, tx = t&15;
  const double* muM = mu + (size_t)m*Cc;
  double muA = muM[i0+lr];
  double muB = muM[j0+lr];
  __syncthreads();
  double acc[4][4] = {};
  for (int kt=0; kt<Nn; kt+=16){
    float4 av = *(const float4*)(F + (size_t)(i0+lr)*Nn + kt + lc);
    float4 bv = *(const float4*)(F + (size_t)(j0+lr)*Nn + kt + lc);
    double mk[4];
    #pragma unroll
    for (int u=0;u<4;u++) mk[u] = (al[kt+lc+u]==k) ? 1.0 : 0.0;
    As[lc+0][lr] = mk[0]*((double)av.x-muA);
    As[lc+1][lr] = mk[1]*((double)av.y-muA);
    As[lc+2][lr] = mk[2]*((double)av.z-muA);
    As[lc+3][lr] = mk[3]*((double)av.w-muA);
    Bs[lc+0][lr] = (double)bv.x-muB;
    Bs[lc+1][lr] = (double)bv.y-muB;
    Bs[lc+2][lr] = (double)bv.z-muB;
    Bs[lc+3][lr] = (double)bv.w-muB;
    __syncthreads();
    #pragma unroll
    for (int kk=0; kk<16; kk++){
      double aa[4], bb[4];
      #pragma unroll
      for (int i=0;i<4;i++) aa[i] = As[kk][ty*4+i];
      #pragma unroll
      for (int j=0;j<4;j++) bb[j] = Bs[kk][tx*4+j];
      #pragma unroll
      for (int i=0;i<4;i++)
        #pragma unroll
        for (int j=0;j<4;j++) acc[i][j] = fma(aa[i], bb[j], acc[i][j]);
    }
    __syncthreads();
  }
  double dv = dvc[m];
  #pragma unroll
  for (int i=0;i<4;i++){
    int gi = i0 + ty*4 + i;
    #pragma unroll
    for (int j=0;j<4;j++){
      int gj = j0 + tx*4 + j;
      double v = acc[i][j]*dv;
      if (gi==gj) v += GAMMA_C;
      A32[(size_t)m*MSZ + (size_t)gi*Cc + gj] = (float)v;
    }
  }
}

__global__ __launch_bounds__(256) void k_power32(const float* __restrict__ A32, float* __restrict__ sarr){
  __shared__ double v[Cc], w[Cc], red[256];
  int m = blockIdx.x, t = threadIdx.x;
  const float* A = A32 + (size_t)m*MSZ;
  for (int i=t;i<Cc;i+=256) v[i] = 1.0;
  __syncthreads();
  int wave = t>>6, lane = t&63;
  for (int it=0; it<POW_ITERS+1; it++){
    for (int r = wave*128; r < wave*128+128; r++){
      const float* row = A + (size_t)r*Cc;
      double pa = 0.0;
      for (int j=lane; j<Cc; j+=64) pa += (double)row[j]*v[j];
      for (int off=32; off>0; off>>=1) pa += __shfl_xor(pa, off);
      if (lane==0) w[r] = pa;
    }
    __syncthreads();
    if (it < POW_ITERS){
      double nn = 0.0;
      for (int i=t;i<Cc;i+=256) nn += w[i]*w[i];
      red[t]=nn; __syncthreads();
      for (int off=128;off>0;off>>=1){ if(t<off) red[t]+=red[t+off]; __syncthreads(); }
      double inv = rsqrt(fmax(red[0], 1e-300));
      __syncthreads();
      for (int i=t;i<Cc;i+=256) v[i] = w[i]*inv;
      __syncthreads();
    }
  }
  double rr = 0.0;
  for (int i=t;i<Cc;i+=256) rr += v[i]*w[i];
  red[t]=rr; __syncthreads();
  for (int off=128;off>0;off>>=1){ if(t<off) red[t]+=red[t+off]; __syncthreads(); }
  if (t==0) sarr[m] = (float)(1.3*red[0] + 1e-6);
}

__global__ void k_sinv(const float* __restrict__ sarr, float* __restrict__ sinv){
  int t = threadIdx.x;
  if (t < NMAT) sinv[t] = 1.f / sarr[t];
}

// init NS: Y0 = cov/s (3-way bf16 split), Z0 = I (3-way)
__global__ __launch_bounds__(256) void k_initsplit3(const float* __restrict__ cov32, const float* __restrict__ sarr,
                                                    short* __restrict__ Y, short* __restrict__ Z,
                                                    size_t PL, int m0){
  int i = blockIdx.x, t = threadIdx.x;
  float rs = 1.f / sarr[m0+i];
  const float* src = cov32 + (size_t)(m0+i)*MSZ;
  size_t base = (size_t)i*MSZ;
  int j0 = blockIdx.y*4096;
  for (int j = j0 + t; j < j0 + 4096; j += 256){
    float v = src[j]*rs;
    short h = f2bs(v);  float r1 = v - b2fs(h);
    short md = f2bs(r1); float r2 = r1 - b2fs(md);
    short lo = f2bs(r2);
    Y[base+j] = h; Y[base+j+PL] = md; Y[base+j+2*PL] = lo;
    int rr = j>>9, cc = j&511;
    Z[base+j]      = (rr==cc) ? (short)0x3F80 : (short)0;
    Z[base+j+PL]   = 0;
    Z[base+j+2*PL] = 0;
  }
}

// 3-way-split bf16 MFMA batched GEMM, 128x128 tile, 4 waves (64x64 each), K-step 32.
// C = A@B (operands symmetric: B read row-wise). MODE 3: C = 1.5I - 0.5*(A@B).
// WF: write fp32 C; else write 3-way split C.
template<int MODE, bool WF>
__global__ __launch_bounds__(256) void bgemm3(const short* __restrict__ A3, const short* __restrict__ B3,
                                              size_t PL, float* __restrict__ Cf, short* __restrict__ C3){
  __shared__ short lA[3][128][40], lB[3][128][40];
  int m = blockIdx.z;
  size_t mb = (size_t)m*MSZ;
  int t = threadIdx.x;
  int i0 = blockIdx.x*128, j0 = blockIdx.y*128;
  int w = t>>6, lane = t&63;
  int wm = w>>1, wn = w&1;
  int fr = lane&15, kq = lane>>4;
  int sr = t>>1, sk = (t&1)*16;
  f4v acc[4][4];
  #pragma unroll
  for (int i=0;i<4;i++)
    #pragma unroll
    for (int j=0;j<4;j++){ f4v z = {0.f,0.f,0.f,0.f}; acc[i][j] = z; }
  const short* ga = A3 + mb + (size_t)(i0+sr)*Cc + sk;
  const short* gb = B3 + mb + (size_t)(j0+sr)*Cc + sk;
  for (int kt=0; kt<Cc; kt+=32){
    #pragma unroll
    for (int pl=0; pl<3; pl++){
      *(s8v*)&lA[pl][sr][sk]   = *(const s8v*)(ga + (size_t)pl*PL + kt);
      *(s8v*)&lA[pl][sr][sk+8] = *(const s8v*)(ga + (size_t)pl*PL + kt + 8);
      *(s8v*)&lB[pl][sr][sk]   = *(const s8v*)(gb + (size_t)pl*PL + kt);
      *(s8v*)&lB[pl][sr][sk+8] = *(const s8v*)(gb + (size_t)pl*PL + kt + 8);
    }
    __syncthreads();
    s8v bh[4], bm[4], bl[4];
    #pragma unroll
    for (int nt=0;nt<4;nt++){
      bh[nt] = *(const s8v*)&lB[0][wn*64+nt*16+fr][kq*8];
      bm[nt] = *(const s8v*)&lB[1][wn*64+nt*16+fr][kq*8];
      bl[nt] = *(const s8v*)&lB[2][wn*64+nt*16+fr][kq*8];
    }
    #pragma unroll
    for (int mt=0;mt<4;mt++){
      s8v ah = *(const s8v*)&lA[0][wm*64+mt*16+fr][kq*8];
      s8v am = *(const s8v*)&lA[1][wm*64+mt*16+fr][kq*8];
      s8v al = *(const s8v*)&lA[2][wm*64+mt*16+fr][kq*8];
      #pragma unroll
      for (int nt=0;nt<4;nt++){
        acc[mt][nt] = __builtin_amdgcn_mfma_f32_16x16x32_bf16(ah, bh[nt], acc[mt][nt], 0,0,0);
        acc[mt][nt] = __builtin_amdgcn_mfma_f32_16x16x32_bf16(ah, bm[nt], acc[mt][nt], 0,0,0);
        acc[mt][nt] = __builtin_amdgcn_mfma_f32_16x16x32_bf16(am, bh[nt], acc[mt][nt], 0,0,0);
        acc[mt][nt] = __builtin_amdgcn_mfma_f32_16x16x32_bf16(ah, bl[nt], acc[mt][nt], 0,0,0);
        acc[mt][nt] = __builtin_amdgcn_mfma_f32_16x16x32_bf16(al, bh[nt], acc[mt][nt], 0,0,0);
        acc[mt][nt] = __builtin_amdgcn_mfma_f32_16x16x32_bf16(am, bm[nt], acc[mt][nt], 0,0,0);
      }
    }
    __syncthreads();
  }
  #pragma unroll
  for (int mt=0;mt<4;mt++){
    #pragma unroll
    for (int nt=0;nt<4;nt++){
      int gj = j0 + wn*64 + nt*16 + fr;
      #pragma unroll
      for (int j=0;j<4;j++){
        int gi = i0 + wm*64 + mt*16 + kq*4 + j;
        float v = acc[mt][nt][j];
        if (MODE==3) v = -0.5f*v + ((gi==gj)?1.5f:0.f);
        size_t idx = mb + (size_t)gi*Cc + gj;
        if (WF) Cf[idx] = v;
        else {
          short h = f2bs(v);  float r1 = v - b2fs(h);
          short md = f2bs(r1); float r2 = r1 - b2fs(md);
          C3[idx] = h; C3[idx+PL] = md; C3[idx+2*PL] = f2bs(r2);
        }
      }
    }
  }
}

// fp32 batched GEMM 128x128, 8x8 micro.
// MODE 0: C=A@B  MODE 2: C=sfac[m]*(A@B)+0.4I  MODE 4: C=sfac[m]*(A@B)  MODE 5: C=1.5A-0.5(A@B)
template<int MODE>
__global__ __launch_bounds__(256) void gemm128(const float* __restrict__ Ab, const float* __restrict__ Bb,
                                               float* __restrict__ Cb, const float* __restrict__ sfac){
  __shared__ float As[16][132], Bs[16][132];
  int m = blockIdx.z;
  const float* A = Ab + (size_t)m*MSZ;
  const float* Bm = Bb + (size_t)m*MSZ;
  float* Cm = Cb + (size_t)m*MSZ;
  int t = threadIdx.x;
  int tx = t&15, ty = t>>4;
  int i0 = blockIdx.x*128, j0 = blockIdx.y*128;
  int ar = t>>2, ac = (t&3)*4;
  int bk = t>>5, bj = (t&31)*4;
  float acc[8][8] = {};
  for (int kt=0; kt<Cc; kt+=16){
    float4 a0 = *(const float4*)(A + (size_t)(i0+ar)*Cc + kt + ac);
    float4 a1 = *(const float4*)(A + (size_t)(i0+ar+64)*Cc + kt + ac);
    float4 b0 = *(const float4*)(Bm + (size_t)(kt+bk)*Cc + j0 + bj);
    float4 b1 = *(const float4*)(Bm + (size_t)(kt+bk+8)*Cc + j0 + bj);
    As[ac+0][ar]=a0.x; As[ac+1][ar]=a0.y; As[ac+2][ar]=a0.z; As[ac+3][ar]=a0.w;
    As[ac+0][ar+64]=a1.x; As[ac+1][ar+64]=a1.y; As[ac+2][ar+64]=a1.z; As[ac+3][ar+64]=a1.w;
    *(float4*)&Bs[bk][bj] = b0;
    *(float4*)&Bs[bk+8][bj] = b1;
    __syncthreads();
    #pragma unroll
    for (int kk=0; kk<16; kk++){
      float4 x0 = *(const float4*)&As[kk][ty*8];
      float4 x1 = *(const float4*)&As[kk][ty*8+4];
      float4 y0 = *(const float4*)&Bs[kk][tx*8];
      float4 y1 = *(const float4*)&Bs[kk][tx*8+4];
      float av[8] = {x0.x,x0.y,x0.z,x0.w,x1.x,x1.y,x1.z,x1.w};
      float bv[8] = {y0.x,y0.y,y0.z,y0.w,y1.x,y1.y,y1.z,y1.w};
      #pragma unroll
      for (int i=0;i<8;i++)
        #pragma unroll
        for (int j=0;j<8;j++) acc[i][j] = fmaf(av[i], bv[j], acc[i][j]);
    }
    __syncthreads();
  }
  float sf = (MODE==2 || MODE==4) ? sfac[m] : 0.f;
  #pragma unroll
  for (int i=0;i<8;i++){
    int gi = i0 + ty*8 + i;
    #pragma unroll
    for (int j=0;j<8;j++){
      int gj = j0 + tx*8 + j;
      float pv = acc[i][j];
      float v;
      if (MODE==2)      v = sf*pv + ((gi==gj)?BETA_C:0.f);
      else if (MODE==4) v = sf*pv;
      else if (MODE==5) v = 1.5f*A[(size_t)gi*Cc + gj] - 0.5f*pv;
      else              v = pv;
      Cm[(size_t)gi*Cc + gj] = v;
    }
  }
}

__global__ __launch_bounds__(256) void k_keep32(const float* __restrict__ Yb, const float* __restrict__ Zb,
                                                float* __restrict__ nsResC, float* __restrict__ styAll, int m0){
  int i = blockIdx.x, t = threadIdx.x;
  int mm = m0 + i;
  const float* src = (mm < 24) ? (Zb + (size_t)i*MSZ) : (Yb + (size_t)i*MSZ);
  float* dst = (mm < 24) ? (nsResC + (size_t)mm*MSZ) : (styAll + (size_t)(mm-24)*MSZ);
  int j0 = blockIdx.y*2048;
  for (int j = j0 + t; j < j0 + 2048; j += 256) dst[j] = src[j];
}

__global__ void k_sfac(const float* __restrict__ sarr, float* __restrict__ sfac){
  int t = threadIdx.x;
  if (t < 24) sfac[t] = ALPHA_C * sqrtf(sarr[24+t] / sarr[t]);
}

__global__ void k_bias64(const double* __restrict__ mu64, float* __restrict__ bias2){
  int m2 = blockIdx.x, t = threadIdx.x;
  bias2[(size_t)m2*Cc + t] = (float)(0.6*mu64[(size_t)(24+m2)*Cc + t] + 0.4*mu64[(size_t)m2*Cc + t]);
}

__global__ __launch_bounds__(256) void k_transfer_d(const float* __restrict__ G, const float* __restrict__ cont,
                                                    const int* __restrict__ assign, const float* __restrict__ mu,
                                                    const float* __restrict__ bias2, float* __restrict__ out){
  __shared__ float As[16][132], Bs[16][132];
  __shared__ unsigned char al2[128];
  int m2 = blockIdx.z; int b = m2/Kk; int k = m2%Kk;
  const float* A = G + (size_t)m2*MSZ;
  const float* F = cont + (size_t)b*Cc*Nn;
  const float* muM = mu + (size_t)m2*Cc;
  int t = threadIdx.x;
  int i0 = blockIdx.x*128, j0 = blockIdx.y*128;
  int ar = t>>2, ac = (t&3)*4;
  int bk = t>>5, bj = (t&31)*4;
  int tx = t&15, ty = t>>4;
  if (t < 128) al2[t] = (unsigned char)assign[b*Nn + j0 + t];
  __syncthreads();
  float acc[8][8] = {};
  for (int kt=0; kt<Cc; kt+=16){
    float4 a0 = *(const float4*)(A + (size_t)(i0+ar)*Cc + kt + ac);
    float4 a1 = *(const float4*)(A + (size_t)(i0+ar+64)*Cc + kt + ac);
    float mb0 = muM[kt+bk], mb1 = muM[kt+bk+8];
    float4 b0 = *(const float4*)(F + (size_t)(kt+bk)*Nn + j0 + bj);
    float4 b1 = *(const float4*)(F + (size_t)(kt+bk+8)*Nn + j0 + bj);
    As[ac+0][ar]=a0.x; As[ac+1][ar]=a0.y; As[ac+2][ar]=a0.z; As[ac+3][ar]=a0.w;
    As[ac+0][ar+64]=a1.x; As[ac+1][ar+64]=a1.y; As[ac+2][ar+64]=a1.z; As[ac+3][ar+64]=a1.w;
    Bs[bk][bj+0]=b0.x-mb0; Bs[bk][bj+1]=b0.y-mb0; Bs[bk][bj+2]=b0.z-mb0; Bs[bk][bj+3]=b0.w-mb0;
    Bs[bk+8][bj+0]=b1.x-mb1; Bs[bk+8][bj+1]=b1.y-mb1; Bs[bk+8][bj+2]=b1.z-mb1; Bs[bk+8][bj+3]=b1.w-mb1;
    __syncthreads();
    #pragma unroll
    for (int kk=0; kk<16; kk++){
      float4 x0 = *(const float4*)&As[kk][ty*8];
      float4 x1 = *(const float4*)&As[kk][ty*8+4];
      float4 y0 = *(const float4*)&Bs[kk][tx*8];
      float4 y1 = *(const float4*)&Bs[kk][tx*8+4];
      float av[8] = {x0.x,x0.y,x0.z,x0.w,x1.x,x1.y,x1.z,x1.w};
      float bv[8] = {y0.x,y0.y,y0.z,y0.w,y1.x,y1.y,y1.z,y1.w};
      #pragma unroll
      for (int i=0;i<8;i++)
        #pragma unroll
        for (int j=0;j<8;j++) acc[i][j] = fmaf(av[i], bv[j], acc[i][j]);
    }
    __syncthreads();
  }
  #pragma unroll
  for (int j=0;j<8;j++){
    int lc2 = tx*8 + j;
    if (al2[lc2] != k) continue;
    int gj = j0 + lc2;
    #pragma unroll
    for (int i=0;i<8;i++){
      int gi = i0 + ty*8 + i;
      out[((size_t)b*Cc + gi)*Nn + gj] = acc[i][j] + bias2[(size_t)m2*Cc + gi];
    }
  }
}

extern "C" void kernel_launch(void* const* d_in, const int* in_sizes, int n_in,
                              void* d_out, int out_size, void* d_ws, size_t ws_size,
                              hipStream_t stream){
  const float* cont = (const float*)d_in[0];
  const float* sty  = (const float*)d_in[1];
  float* out = (float*)d_out;

  char* w = (char*)d_ws;
  size_t off = 0;
  auto alloc = [&](size_t bytes) -> void* {
    void* pp = (void*)(w + off);
    off = (off + bytes + 255) & ~(size_t)255;
    return pp;
  };
  float*  cent32 = (float*) alloc((size_t)NMAT*Cc*4);
  float*  csq32  = (float*) alloc((size_t)NMAT*4);
  float*  xsq32  = (float*) alloc((size_t)Pp*Nn*4);
  double* csum64 = (double*)alloc((size_t)NMAT*Cc*8);
  float*  cntf   = (float*) alloc((size_t)NMAT*4);
  double* mu64   = (double*)alloc((size_t)NMAT*Cc*8);
  float*  mu32   = (float*) alloc((size_t)NMAT*Cc*4);
  double* dvc64  = (double*)alloc((size_t)NMAT*8);
  float*  sarr   = (float*) alloc((size_t)NMAT*4);
  float*  sinv   = (float*) alloc((size_t)NMAT*4);
  float*  sfac   = (float*) alloc((size_t)24*4);
  float*  bias2  = (float*) alloc((size_t)24*Cc*4);
  int*    assign = (int*)   alloc((size_t)Pp*Nn*4);
  float*  G      = (float*) alloc((size_t)24*MSZ*4);   // 24 MiB (doubles as NS state C)
  float*  nsResC = (float*) alloc((size_t)24*MSZ*4);   // 24 MiB
  float*  styAll = (float*) alloc((size_t)24*MSZ*4);   // 24 MiB
  float*  cov32  = (float*) alloc((size_t)NMAT*MSZ*4); // 48 MiB
  short*  nsX    = (short*) alloc((size_t)3*NSB16*MSZ*2); // 24 MiB (NS state D)
  (void)ws_size; (void)in_sizes; (void)n_in; (void)out_size;

  // d_out 64 MiB: NS states A (0..24MiB), B (24..48MiB), fp32 X spare (48..64MiB).
  // During refine the dead state regions become fp32 temps R0/R1/R2.
  const size_t PL = (size_t)NSB16*MSZ;   // shorts per plane (8 MiB)
  char* db = (char*)d_out;
  short* st[4];
  st[0] = (short*)db;
  st[1] = (short*)(db + (size_t)24*1024*1024);
  st[2] = (short*)G;
  st[3] = nsX;
  float* spareX = (float*)(db + (size_t)48*1024*1024);
  float* R0 = (float*)db;
  float* R1 = (float*)(db + (size_t)16*1024*1024);
  float* R2 = (float*)(db + (size_t)32*1024*1024);

  // ---- ideal-fp32 k-means ----
  k_init_cent32<<<NMAT, Cc, 0, stream>>>(cont, sty, cent32);
  k_xsq32<<<dim3(Pp,16), 256, 0, stream>>>(cont, sty, xsq32);
  for (int it=0; it<10; ++it){
    k_csq32<<<1, 64, 0, stream>>>(cent32, csq32);
    k_assign_i32<<<dim3(Pp,16), 256, 0, stream>>>(cont, sty, cent32, csq32, xsq32, assign);
    k_update64<<<dim3(Pp,8), 256, 0, stream>>>(cont, sty, assign, csum64, cntf);
    k_centupd32<<<NMAT, Cc, 0, stream>>>(csum64, cntf, cent32);
  }
  k_csq32<<<1, 64, 0, stream>>>(cent32, csq32);
  k_assign_i32<<<dim3(Pp,16), 256, 0, stream>>>(cont, sty, cent32, csq32, xsq32, assign);

  // ---- stats ----
  k_update64<<<dim3(Pp,8), 256, 0, stream>>>(cont, sty, assign, csum64, cntf);
  k_mu64<<<NMAT, Cc, 0, stream>>>(csum64, cntf, mu64, mu32, dvc64);
  k_covd32<<<dim3(8,8,NMAT), 256, 0, stream>>>(cont, sty, assign, mu64, dvc64, cov32);
  k_power32<<<NMAT, 256, 0, stream>>>(cov32, sarr);
  k_sinv<<<1, 64, 0, stream>>>(sarr, sinv);
  k_sfac<<<1, 32, 0, stream>>>(sarr, sfac);
  k_bias64<<<24, Cc, 0, stream>>>(mu64, bias2);

  // ---- 3-way-split bf16 MFMA Newton-Schulz + fp32 Newton refine, 3 batches of 16 ----
  for (int bt=0; bt<NMAT/NSB16; ++bt){
    int m0 = bt*NSB16;
    int py=0, pz=1, pt=2, sp=3;
    k_initsplit3<<<dim3(NSB16,64), 256, 0, stream>>>(cov32, sarr, st[py], st[pz], PL, m0);
    for (int it=0; it<NSB_ITERS; ++it){
      bool last = (it == NSB_ITERS-1);
      bgemm3<3,false><<<dim3(4,4,NSB16), 256, 0, stream>>>(st[pz], st[py], PL, nullptr, st[pt]);
      if (!last){
        bgemm3<0,false><<<dim3(4,4,NSB16), 256, 0, stream>>>(st[py], st[pt], PL, nullptr, st[sp]);
        bgemm3<0,false><<<dim3(4,4,NSB16), 256, 0, stream>>>(st[pt], st[pz], PL, nullptr, st[py]);
        int opy=py, opz=pz;
        py = sp; pz = opy; sp = opz;   // pt unchanged
      } else {
        bgemm3<0,true><<<dim3(4,4,NSB16), 256, 0, stream>>>(st[pt], st[pz], PL, spareX, nullptr);
      }
    }
    // fp32 Newton refine: X <- 1.5X - 0.5 X (Ahat X^2), 2 rounds; then Y = Ahat X
    float* X  = spareX;
    float* T1 = R0;
    float* T2 = R1;
    float* T3 = R2;
    for (int r=0; r<2; ++r){
      gemm128<0><<<dim3(4,4,NSB16), 256, 0, stream>>>(X, X, T1, nullptr);
      gemm128<4><<<dim3(4,4,NSB16), 256, 0, stream>>>(cov32 + (size_t)m0*MSZ, T1, T2, sinv + m0);
      gemm128<5><<<dim3(4,4,NSB16), 256, 0, stream>>>(X, T2, T3, nullptr);
      float* tmp = X; X = T3; T3 = tmp;
    }
    gemm128<4><<<dim3(4,4,NSB16), 256, 0, stream>>>(cov32 + (size_t)m0*MSZ, X, T1, sinv + m0);
    k_keep32<<<dim3(NSB16,128), 256, 0, stream>>>(T1, X, nsResC, styAll, m0);
  }

  // ---- G = sfac*(Y_style @ Z_content) + 0.4 I ----
  gemm128<2><<<dim3(4,4,24), 256, 0, stream>>>(styAll, nsResC, G, sfac);

  // ---- apply transform + blend, direct masked write ----
  k_transfer_d<<<dim3(4,32,24), 256, 0, stream>>>(G, cont, assign, mu32, bias2, out);
}

// Round 17
// 15951.031 us; speedup vs baseline: 3.3370x; 1.2488x over previous
//
#include <hip/hip_runtime.h>
#include <math.h>
#include <cstddef>

#define Bn 8
#define Cc 512
#define Nn 4096
#define Kk 3
#define Pp 16
#define NMAT 48
#define MSZ (Cc*Cc)
#define ALPHA_C 0.6f
#define BETA_C 0.4f
#define GAMMA_C 0.1
#define POW_ITERS 8
#define NSB_ITERS 16
#define NS_SWITCH 7
#define NSB16 16

using s8v = __attribute__((ext_vector_type(8))) short;
using f4v = __attribute__((ext_vector_type(4))) float;

__device__ __forceinline__ float b2fs(short u){
  union { unsigned i; float f; } x; x.i = ((unsigned)(unsigned short)u) << 16; return x.f;
}
__device__ __forceinline__ short f2bs(float f){
  unsigned u = __float_as_uint(f);
  unsigned r = (u + 0x7FFF + ((u >> 16) & 1)) >> 16;
  return (short)r;
}

__device__ __forceinline__ const float* Fbase(const float* cont, const float* sty, int p){
  return (p < Bn) ? (cont + (size_t)p*Cc*Nn) : (sty + (size_t)(p-Bn)*Cc*Nn);
}

// ===== ideal-fp32 k-means (round-13 verified arithmetic: DO NOT TOUCH) =====
__global__ void k_init_cent32(const float* __restrict__ cont, const float* __restrict__ sty,
                              float* __restrict__ cent32){
  int m = blockIdx.x; int p = m/Kk, k = m%Kk;
  const int ninit[3] = {0, 2047, 4095};
  const float* F = Fbase(cont, sty, p);
  int c = threadIdx.x;
  cent32[(size_t)m*Cc + c] = F[(size_t)c*Nn + ninit[k]];
}

__global__ __launch_bounds__(256) void k_xsq32(const float* __restrict__ cont, const float* __restrict__ sty,
                                               float* __restrict__ xsq32){
  int p = blockIdx.x;
  int n = blockIdx.y*256 + threadIdx.x;
  const float* F = Fbase(cont, sty, p);
  double s = 0.0;
  for (int c=0; c<Cc; c++){ double v = (double)F[(size_t)c*Nn + n]; s += v*v; }
  xsq32[p*Nn + n] = (float)s;
}

// assign with in-block csq (same sequential fp64 order as before -> bit-identical)
__global__ __launch_bounds__(256) void k_assign_f(const float* __restrict__ cont, const float* __restrict__ sty,
                                                  const float* __restrict__ cent32,
                                                  const float* __restrict__ xsq32, int* __restrict__ assign){
  __shared__ float cl[Kk][Cc];
  __shared__ float csqs[Kk];
  int p = blockIdx.x, t = threadIdx.x;
  const float* F = Fbase(cont, sty, p);
  for (int i=t; i<Kk*Cc; i+=256) ((float*)cl)[i] = cent32[(size_t)p*Kk*Cc + i];
  __syncthreads();
  if (t < Kk){
    double s = 0.0;
    for (int i=0;i<Cc;i++){ double v = (double)cl[t][i]; s += v*v; }
    csqs[t] = (float)s;
  }
  __syncthreads();
  float cs0 = csqs[0], cs1 = csqs[1], cs2 = csqs[2];
  int n = blockIdx.y*256 + t;
  const float* col = F + n;
  double d0=0.0, d1=0.0, d2=0.0;
  for (int c=0; c<Cc; c++){
    double f = (double)col[(size_t)c*Nn];
    d0 += f*(double)cl[0][c];
    d1 += f*(double)cl[1][c];
    d2 += f*(double)cl[2][c];
  }
  float f0 = (float)d0, f1 = (float)d1, f2 = (float)d2;
  float xs = xsq32[p*Nn + n];
  float D0, D1, D2;
  {
    #pragma clang fp contract(off)
    D0 = (xs - 2.f*f0) + cs0;
    D1 = (xs - 2.f*f1) + cs1;
    D2 = (xs - 2.f*f2) + cs2;
  }
  int a = 0; float best = D0;
  if (D1 < best){ best = D1; a = 1; }
  if (D2 < best){ best = D2; a = 2; }
  assign[p*Nn + n] = a;
}

__global__ __launch_bounds__(256) void k_update64(const float* __restrict__ cont, const float* __restrict__ sty,
                                                  const int* __restrict__ assign,
                                                  double* __restrict__ csum, float* __restrict__ cntf){
  __shared__ unsigned char al[Nn];
  __shared__ int ri[256];
  int p = blockIdx.x, cg = blockIdx.y, t = threadIdx.x;
  const float* F = Fbase(cont, sty, p);
  for (int i=t; i<Nn; i+=256) al[i] = (unsigned char)assign[p*Nn+i];
  __syncthreads();
  int wave = t>>6, lane = t&63;
  for (int rr=0; rr<16; rr++){
    int r = cg*64 + wave*16 + rr;
    const float* row = F + (size_t)r*Nn;
    double s0=0.0,s1=0.0,s2=0.0;
    for (int n=lane; n<Nn; n+=64){
      double f = (double)row[n]; int a = al[n];
      s0 += (a==0)?f:0.0; s1 += (a==1)?f:0.0; s2 += (a==2)?f:0.0;
    }
    for (int off=32; off>0; off>>=1){
      s0 += __shfl_xor(s0,off); s1 += __shfl_xor(s1,off); s2 += __shfl_xor(s2,off);
    }
    if (lane==0){
      csum[((size_t)p*Kk+0)*Cc + r] = s0;
      csum[((size_t)p*Kk+1)*Cc + r] = s1;
      csum[((size_t)p*Kk+2)*Cc + r] = s2;
    }
  }
  if (cg==0){
    int c0=0,c1=0,c2=0;
    for (int n=t;n<Nn;n+=256){ int a=al[n]; c0+=(a==0); c1+=(a==1); c2+=(a==2); }
    for (int k=0;k<3;k++){
      int v = (k==0)?c0:((k==1)?c1:c2);
      ri[t] = v; __syncthreads();
      for (int off=128; off>0; off>>=1){ if(t<off) ri[t]+=ri[t+off]; __syncthreads(); }
      if (t==0) cntf[p*Kk+k] = (float)ri[0];
      __syncthreads();
    }
  }
}

__global__ void k_centupd32(const double* __restrict__ csum, const float* __restrict__ cntf,
                            float* __restrict__ cent32){
  int m = blockIdx.x, c = threadIdx.x;
  float n = cntf[m];
  if (n > 0.f){
    float s32 = (float)csum[(size_t)m*Cc + c];
    cent32[(size_t)m*Cc + c] = s32 / fmaxf(n, 1.f);
  }
}

__global__ void k_mu64(const double* __restrict__ csum, const float* __restrict__ cntf,
                       double* __restrict__ mu64, float* __restrict__ mu32, float* __restrict__ dvc32){
  int m = blockIdx.x, t = threadIdx.x;
  double n = fmax((double)cntf[m], 1.0);
  double v = csum[(size_t)m*Cc+t] / n;
  mu64[(size_t)m*Cc+t] = v;
  mu32[(size_t)m*Cc+t] = (float)v;
  if (t==0) dvc32[m] = (float)(1.0 / fmax(n-1.0, 1.0));
}

// cov: fp32, lower-triangle blocks only + mirror write. Mask on A side (symmetric).
__global__ __launch_bounds__(256) void k_covf32(const float* __restrict__ cont, const float* __restrict__ sty,
                                                const int* __restrict__ assign, const float* __restrict__ mu32,
                                                const float* __restrict__ dvc32, float* __restrict__ A32){
  if (blockIdx.y > blockIdx.x) return;
  __shared__ float As[16][68], Bs[16][68];
  __shared__ unsigned char al[Nn];
  int m = blockIdx.z; int p = m/Kk; int k = m%Kk;
  const float* F = Fbase(cont, sty, p);
  int t = threadIdx.x;
  for (int i=t; i<Nn; i+=256) al[i] = (unsigned char)assign[p*Nn+i];
  int i0 = blockIdx.x*64, j0 = blockIdx.y*64;
  int lr = t>>2, lc = (t&3)*4;
  int ty = t>>4, tx = t&15;
  const float* muM = mu32 + (size_t)m*Cc;
  float muA = muM[i0+lr];
  float muB = muM[j0+lr];
  __syncthreads();
  float acc[4][4] = {};
  for (int kt=0; kt<Nn; kt+=16){
    float4 av = *(const float4*)(F + (size_t)(i0+lr)*Nn + kt + lc);
    float4 bv = *(const float4*)(F + (size_t)(j0+lr)*Nn + kt + lc);
    float mk[4];
    #pragma unroll
    for (int u=0;u<4;u++) mk[u] = (al[kt+lc+u]==k) ? 1.f : 0.f;
    As[lc+0][lr] = mk[0]*(av.x-muA);
    As[lc+1][lr] = mk[1]*(av.y-muA);
    As[lc+2][lr] = mk[2]*(av.z-muA);
    As[lc+3][lr] = mk[3]*(av.w-muA);
    Bs[lc+0][lr] = bv.x-muB;
    Bs[lc+1][lr] = bv.y-muB;
    Bs[lc+2][lr] = bv.z-muB;
    Bs[lc+3][lr] = bv.w-muB;
    __syncthreads();
    #pragma unroll
    for (int kk=0; kk<16; kk++){
      float aa[4], bb[4];
      #pragma unroll
      for (int i=0;i<4;i++) aa[i] = As[kk][ty*4+i];
      #pragma unroll
      for (int j=0;j<4;j++) bb[j] = Bs[kk][tx*4+j];
      #pragma unroll
      for (int i=0;i<4;i++)
        #pragma unroll
        for (int j=0;j<4;j++) acc[i][j] = fmaf(aa[i], bb[j], acc[i][j]);
    }
    __syncthreads();
  }
  float dv = dvc32[m];
  #pragma unroll
  for (int i=0;i<4;i++){
    int gi = i0 + ty*4 + i;
    #pragma unroll
    for (int j=0;j<4;j++){
      int gj = j0 + tx*4 + j;
      float v = acc[i][j]*dv;
      if (gi==gj) v += (float)GAMMA_C;
      A32[(size_t)m*MSZ + (size_t)gi*Cc + gj] = v;
      A32[(size_t)m*MSZ + (size_t)gj*Cc + gi] = v;
    }
  }
}

__global__ __launch_bounds__(256) void k_power32(const float* __restrict__ A32, float* __restrict__ sarr){
  __shared__ double v[Cc], w[Cc], red[256];
  int m = blockIdx.x, t = threadIdx.x;
  const float* A = A32 + (size_t)m*MSZ;
  for (int i=t;i<Cc;i+=256) v[i] = 1.0;
  __syncthreads();
  int wave = t>>6, lane = t&63;
  for (int it=0; it<POW_ITERS+1; it++){
    for (int r = wave*128; r < wave*128+128; r++){
      const float* row = A + (size_t)r*Cc;
      double pa = 0.0;
      for (int j=lane; j<Cc; j+=64) pa += (double)row[j]*v[j];
      for (int off=32; off>0; off>>=1) pa += __shfl_xor(pa, off);
      if (lane==0) w[r] = pa;
    }
    __syncthreads();
    if (it < POW_ITERS){
      double nn = 0.0;
      for (int i=t;i<Cc;i+=256) nn += w[i]*w[i];
      red[t]=nn; __syncthreads();
      for (int off=128;off>0;off>>=1){ if(t<off) red[t]+=red[t+off]; __syncthreads(); }
      double inv = rsqrt(fmax(red[0], 1e-300));
      __syncthreads();
      for (int i=t;i<Cc;i+=256) v[i] = w[i]*inv;
      __syncthreads();
    }
  }
  double rr = 0.0;
  for (int i=t;i<Cc;i+=256) rr += v[i]*w[i];
  red[t]=rr; __syncthreads();
  for (int off=128;off>0;off>>=1){ if(t<off) red[t]+=red[t+off]; __syncthreads(); }
  if (t==0) sarr[m] = (float)(1.3*red[0] + 1e-6);
}

__global__ void k_sinv(const float* __restrict__ sarr, float* __restrict__ sinv){
  int t = threadIdx.x;
  if (t < NMAT) sinv[t] = 1.f / sarr[t];
}

// init NS: Y0 = cov/s (3-way bf16 split), Z0 = I (3-way)
__global__ __launch_bounds__(256) void k_initsplit3(const float* __restrict__ cov32, const float* __restrict__ sarr,
                                                    short* __restrict__ Y, short* __restrict__ Z,
                                                    size_t PL, int m0){
  int i = blockIdx.x, t = threadIdx.x;
  float rs = 1.f / sarr[m0+i];
  const float* src = cov32 + (size_t)(m0+i)*MSZ;
  size_t base = (size_t)i*MSZ;
  int j0 = blockIdx.y*4096;
  for (int j = j0 + t; j < j0 + 4096; j += 256){
    float v = src[j]*rs;
    short h = f2bs(v);  float r1 = v - b2fs(h);
    short md = f2bs(r1); float r2 = r1 - b2fs(md);
    short lo = f2bs(r2);
    Y[base+j] = h; Y[base+j+PL] = md; Y[base+j+2*PL] = lo;
    int rr = j>>9, cc = j&511;
    Z[base+j]      = (rr==cc) ? (short)0x3F80 : (short)0;
    Z[base+j+PL]   = 0;
    Z[base+j+2*PL] = 0;
  }
}

// split-bf16 MFMA batched GEMM, 128x128 tile, 4 waves, K-step 32.
// NPROD=6: 3-plane (hh,hm,mh,hl,lh,mm). NPROD=3: 2-plane (hh,hm,mh).
// MODE 3: C = 1.5I - 0.5*(A@B). WF: write fp32 C; else write split C (NPROD planes' worth).
template<int MODE, bool WF, int NPROD>
__global__ __launch_bounds__(256) void bgemm3(const short* __restrict__ A3, const short* __restrict__ B3,
                                              size_t PL, float* __restrict__ Cf, short* __restrict__ C3){
  __shared__ short lA[3][128][40], lB[3][128][40];
  const int NPL = (NPROD==6) ? 3 : 2;
  int m = blockIdx.z;
  size_t mb = (size_t)m*MSZ;
  int t = threadIdx.x;
  int i0 = blockIdx.x*128, j0 = blockIdx.y*128;
  int w = t>>6, lane = t&63;
  int wm = w>>1, wn = w&1;
  int fr = lane&15, kq = lane>>4;
  int sr = t>>1, sk = (t&1)*16;
  f4v acc[4][4];
  #pragma unroll
  for (int i=0;i<4;i++)
    #pragma unroll
    for (int j=0;j<4;j++){ f4v z = {0.f,0.f,0.f,0.f}; acc[i][j] = z; }
  const short* ga = A3 + mb + (size_t)(i0+sr)*Cc + sk;
  const short* gb = B3 + mb + (size_t)(j0+sr)*Cc + sk;
  for (int kt=0; kt<Cc; kt+=32){
    #pragma unroll
    for (int pl=0; pl<NPL; pl++){
      *(s8v*)&lA[pl][sr][sk]   = *(const s8v*)(ga + (size_t)pl*PL + kt);
      *(s8v*)&lA[pl][sr][sk+8] = *(const s8v*)(ga + (size_t)pl*PL + kt + 8);
      *(s8v*)&lB[pl][sr][sk]   = *(const s8v*)(gb + (size_t)pl*PL + kt);
      *(s8v*)&lB[pl][sr][sk+8] = *(const s8v*)(gb + (size_t)pl*PL + kt + 8);
    }
    __syncthreads();
    s8v bh[4], bm[4], bl[4];
    #pragma unroll
    for (int nt=0;nt<4;nt++){
      bh[nt] = *(const s8v*)&lB[0][wn*64+nt*16+fr][kq*8];
      bm[nt] = *(const s8v*)&lB[1][wn*64+nt*16+fr][kq*8];
      if (NPROD==6) bl[nt] = *(const s8v*)&lB[2][wn*64+nt*16+fr][kq*8];
    }
    #pragma unroll
    for (int mt=0;mt<4;mt++){
      s8v ah = *(const s8v*)&lA[0][wm*64+mt*16+fr][kq*8];
      s8v am = *(const s8v*)&lA[1][wm*64+mt*16+fr][kq*8];
      s8v al;
      if (NPROD==6) al = *(const s8v*)&lA[2][wm*64+mt*16+fr][kq*8];
      #pragma unroll
      for (int nt=0;nt<4;nt++){
        acc[mt][nt] = __builtin_amdgcn_mfma_f32_16x16x32_bf16(ah, bh[nt], acc[mt][nt], 0,0,0);
        acc[mt][nt] = __builtin_amdgcn_mfma_f32_16x16x32_bf16(ah, bm[nt], acc[mt][nt], 0,0,0);
        acc[mt][nt] = __builtin_amdgcn_mfma_f32_16x16x32_bf16(am, bh[nt], acc[mt][nt], 0,0,0);
        if (NPROD==6){
          acc[mt][nt] = __builtin_amdgcn_mfma_f32_16x16x32_bf16(ah, bl[nt], acc[mt][nt], 0,0,0);
          acc[mt][nt] = __builtin_amdgcn_mfma_f32_16x16x32_bf16(al, bh[nt], acc[mt][nt], 0,0,0);
          acc[mt][nt] = __builtin_amdgcn_mfma_f32_16x16x32_bf16(am, bm[nt], acc[mt][nt], 0,0,0);
        }
      }
    }
    __syncthreads();
  }
  #pragma unroll
  for (int mt=0;mt<4;mt++){
    #pragma unroll
    for (int nt=0;nt<4;nt++){
      int gj = j0 + wn*64 + nt*16 + fr;
      #pragma unroll
      for (int j=0;j<4;j++){
        int gi = i0 + wm*64 + mt*16 + kq*4 + j;
        float v = acc[mt][nt][j];
        if (MODE==3) v = -0.5f*v + ((gi==gj)?1.5f:0.f);
        size_t idx = mb + (size_t)gi*Cc + gj;
        if (WF) Cf[idx] = v;
        else {
          short h = f2bs(v);  float r1 = v - b2fs(h);
          short md = f2bs(r1);
          C3[idx] = h; C3[idx+PL] = md;
          if (NPROD==6){ float r2 = r1 - b2fs(md); C3[idx+2*PL] = f2bs(r2); }
        }
      }
    }
  }
}

// fp32 batched GEMM 128x128, 8x8 micro.
// MODE 0: C=A@B  MODE 2: C=sfac[m]*(A@B)+0.4I  MODE 4: C=sfac[m]*(A@B)  MODE 5: C=1.5A-0.5(A@B)
template<int MODE>
__global__ __launch_bounds__(256) void gemm128(const float* __restrict__ Ab, const float* __restrict__ Bb,
                                               float* __restrict__ Cb, const float* __restrict__ sfac){
  __shared__ float As[16][132], Bs[16][132];
  int m = blockIdx.z;
  const float* A = Ab + (size_t)m*MSZ;
  const float* Bm = Bb + (size_t)m*MSZ;
  float* Cm = Cb + (size_t)m*MSZ;
  int t = threadIdx.x;
  int tx = t&15, ty = t>>4;
  int i0 = blockIdx.x*128, j0 = blockIdx.y*128;
  int ar = t>>2, ac = (t&3)*4;
  int bk = t>>5, bj = (t&31)*4;
  float acc[8][8] = {};
  for (int kt=0; kt<Cc; kt+=16){
    float4 a0 = *(const float4*)(A + (size_t)(i0+ar)*Cc + kt + ac);
    float4 a1 = *(const float4*)(A + (size_t)(i0+ar+64)*Cc + kt + ac);
    float4 b0 = *(const float4*)(Bm + (size_t)(kt+bk)*Cc + j0 + bj);
    float4 b1 = *(const float4*)(Bm + (size_t)(kt+bk+8)*Cc + j0 + bj);
    As[ac+0][ar]=a0.x; As[ac+1][ar]=a0.y; As[ac+2][ar]=a0.z; As[ac+3][ar]=a0.w;
    As[ac+0][ar+64]=a1.x; As[ac+1][ar+64]=a1.y; As[ac+2][ar+64]=a1.z; As[ac+3][ar+64]=a1.w;
    *(float4*)&Bs[bk][bj] = b0;
    *(float4*)&Bs[bk+8][bj] = b1;
    __syncthreads();
    #pragma unroll
    for (int kk=0; kk<16; kk++){
      float4 x0 = *(const float4*)&As[kk][ty*8];
      float4 x1 = *(const float4*)&As[kk][ty*8+4];
      float4 y0 = *(const float4*)&Bs[kk][tx*8];
      float4 y1 = *(const float4*)&Bs[kk][tx*8+4];
      float av[8] = {x0.x,x0.y,x0.z,x0.w,x1.x,x1.y,x1.z,x1.w};
      float bv[8] = {y0.x,y0.y,y0.z,y0.w,y1.x,y1.y,y1.z,y1.w};
      #pragma unroll
      for (int i=0;i<8;i++)
        #pragma unroll
        for (int j=0;j<8;j++) acc[i][j] = fmaf(av[i], bv[j], acc[i][j]);
    }
    __syncthreads();
  }
  float sf = (MODE==2 || MODE==4) ? sfac[m] : 0.f;
  #pragma unroll
  for (int i=0;i<8;i++){
    int gi = i0 + ty*8 + i;
    #pragma unroll
    for (int j=0;j<8;j++){
      int gj = j0 + tx*8 + j;
      float pv = acc[i][j];
      float v;
      if (MODE==2)      v = sf*pv + ((gi==gj)?BETA_C:0.f);
      else if (MODE==4) v = sf*pv;
      else if (MODE==5) v = 1.5f*A[(size_t)gi*Cc + gj] - 0.5f*pv;
      else              v = pv;
      Cm[(size_t)gi*Cc + gj] = v;
    }
  }
}

__global__ __launch_bounds__(256) void k_keep32(const float* __restrict__ Yb, const float* __restrict__ Zb,
                                                float* __restrict__ nsResC, float* __restrict__ styAll, int m0){
  int i = blockIdx.x, t = threadIdx.x;
  int mm = m0 + i;
  const float* src = (mm < 24) ? (Zb + (size_t)i*MSZ) : (Yb + (size_t)i*MSZ);
  float* dst = (mm < 24) ? (nsResC + (size_t)mm*MSZ) : (styAll + (size_t)(mm-24)*MSZ);
  int j0 = blockIdx.y*2048;
  for (int j = j0 + t; j < j0 + 2048; j += 256) dst[j] = src[j];
}

__global__ void k_sfac(const float* __restrict__ sarr, float* __restrict__ sfac){
  int t = threadIdx.x;
  if (t < 24) sfac[t] = ALPHA_C * sqrtf(sarr[24+t] / sarr[t]);
}

__global__ void k_bias64(const double* __restrict__ mu64, float* __restrict__ bias2){
  int m2 = blockIdx.x, t = threadIdx.x;
  bias2[(size_t)m2*Cc + t] = (float)(0.6*mu64[(size_t)(24+m2)*Cc + t] + 0.4*mu64[(size_t)m2*Cc + t]);
}

__global__ __launch_bounds__(256) void k_transfer_d(const float* __restrict__ G, const float* __restrict__ cont,
                                                    const int* __restrict__ assign, const float* __restrict__ mu,
                                                    const float* __restrict__ bias2, float* __restrict__ out){
  __shared__ float As[16][132], Bs[16][132];
  __shared__ unsigned char al2[128];
  int m2 = blockIdx.z; int b = m2/Kk; int k = m2%Kk;
  const float* A = G + (size_t)m2*MSZ;
  const float* F = cont + (size_t)b*Cc*Nn;
  const float* muM = mu + (size_t)m2*Cc;
  int t = threadIdx.x;
  int i0 = blockIdx.x*128, j0 = blockIdx.y*128;
  int ar = t>>2, ac = (t&3)*4;
  int bk = t>>5, bj = (t&31)*4;
  int tx = t&15, ty = t>>4;
  if (t < 128) al2[t] = (unsigned char)assign[b*Nn + j0 + t];
  __syncthreads();
  float acc[8][8] = {};
  for (int kt=0; kt<Cc; kt+=16){
    float4 a0 = *(const float4*)(A + (size_t)(i0+ar)*Cc + kt + ac);
    float4 a1 = *(const float4*)(A + (size_t)(i0+ar+64)*Cc + kt + ac);
    float mb0 = muM[kt+bk], mb1 = muM[kt+bk+8];
    float4 b0 = *(const float4*)(F + (size_t)(kt+bk)*Nn + j0 + bj);
    float4 b1 = *(const float4*)(F + (size_t)(kt+bk+8)*Nn + j0 + bj);
    As[ac+0][ar]=a0.x; As[ac+1][ar]=a0.y; As[ac+2][ar]=a0.z; As[ac+3][ar]=a0.w;
    As[ac+0][ar+64]=a1.x; As[ac+1][ar+64]=a1.y; As[ac+2][ar+64]=a1.z; As[ac+3][ar+64]=a1.w;
    Bs[bk][bj+0]=b0.x-mb0; Bs[bk][bj+1]=b0.y-mb0; Bs[bk][bj+2]=b0.z-mb0; Bs[bk][bj+3]=b0.w-mb0;
    Bs[bk+8][bj+0]=b1.x-mb1; Bs[bk+8][bj+1]=b1.y-mb1; Bs[bk+8][bj+2]=b1.z-mb1; Bs[bk+8][bj+3]=b1.w-mb1;
    __syncthreads();
    #pragma unroll
    for (int kk=0; kk<16; kk++){
      float4 x0 = *(const float4*)&As[kk][ty*8];
      float4 x1 = *(const float4*)&As[kk][ty*8+4];
      float4 y0 = *(const float4*)&Bs[kk][tx*8];
      float4 y1 = *(const float4*)&Bs[kk][tx*8+4];
      float av[8] = {x0.x,x0.y,x0.z,x0.w,x1.x,x1.y,x1.z,x1.w};
      float bv[8] = {y0.x,y0.y,y0.z,y0.w,y1.x,y1.y,y1.z,y1.w};
      #pragma unroll
      for (int i=0;i<8;i++)
        #pragma unroll
        for (int j=0;j<8;j++) acc[i][j] = fmaf(av[i], bv[j], acc[i][j]);
    }
    __syncthreads();
  }
  #pragma unroll
  for (int j=0;j<8;j++){
    int lc2 = tx*8 + j;
    if (al2[lc2] != k) continue;
    int gj = j0 + lc2;
    #pragma unroll
    for (int i=0;i<8;i++){
      int gi = i0 + ty*8 + i;
      out[((size_t)b*Cc + gi)*Nn + gj] = acc[i][j] + bias2[(size_t)m2*Cc + gi];
    }
  }
}

extern "C" void kernel_launch(void* const* d_in, const int* in_sizes, int n_in,
                              void* d_out, int out_size, void* d_ws, size_t ws_size,
                              hipStream_t stream){
  const float* cont = (const float*)d_in[0];
  const float* sty  = (const float*)d_in[1];
  float* out = (float*)d_out;

  char* w = (char*)d_ws;
  size_t off = 0;
  auto alloc = [&](size_t bytes) -> void* {
    void* pp = (void*)(w + off);
    off = (off + bytes + 255) & ~(size_t)255;
    return pp;
  };
  float*  cent32 = (float*) alloc((size_t)NMAT*Cc*4);
  float*  xsq32  = (float*) alloc((size_t)Pp*Nn*4);
  double* csum64 = (double*)alloc((size_t)NMAT*Cc*8);
  float*  cntf   = (float*) alloc((size_t)NMAT*4);
  double* mu64   = (double*)alloc((size_t)NMAT*Cc*8);
  float*  mu32   = (float*) alloc((size_t)NMAT*Cc*4);
  float*  dvc32  = (float*) alloc((size_t)NMAT*4);
  float*  sarr   = (float*) alloc((size_t)NMAT*4);
  float*  sinv   = (float*) alloc((size_t)NMAT*4);
  float*  sfac   = (float*) alloc((size_t)24*4);
  float*  bias2  = (float*) alloc((size_t)24*Cc*4);
  int*    assign = (int*)   alloc((size_t)Pp*Nn*4);
  float*  G      = (float*) alloc((size_t)24*MSZ*4);   // 24 MiB (doubles as NS state C)
  float*  nsResC = (float*) alloc((size_t)24*MSZ*4);   // 24 MiB
  float*  styAll = (float*) alloc((size_t)24*MSZ*4);   // 24 MiB
  float*  cov32  = (float*) alloc((size_t)NMAT*MSZ*4); // 48 MiB
  short*  nsX    = (short*) alloc((size_t)3*NSB16*MSZ*2); // 24 MiB (NS state D)
  (void)ws_size; (void)in_sizes; (void)n_in; (void)out_size;

  // d_out 64 MiB: NS states A (0..24MiB), B (24..48MiB), fp32 X spare (48..64MiB).
  // During refine the dead state regions become fp32 temps R0/R1/R2.
  const size_t PL = (size_t)NSB16*MSZ;   // shorts per plane (8 MiB)
  char* db = (char*)d_out;
  short* st[4];
  st[0] = (short*)db;
  st[1] = (short*)(db + (size_t)24*1024*1024);
  st[2] = (short*)G;
  st[3] = nsX;
  float* spareX = (float*)(db + (size_t)48*1024*1024);
  float* R0 = (float*)db;
  float* R1 = (float*)(db + (size_t)16*1024*1024);
  float* R2 = (float*)(db + (size_t)32*1024*1024);

  // ---- ideal-fp32 k-means ----
  k_init_cent32<<<NMAT, Cc, 0, stream>>>(cont, sty, cent32);
  k_xsq32<<<dim3(Pp,16), 256, 0, stream>>>(cont, sty, xsq32);
  for (int it=0; it<10; ++it){
    k_assign_f<<<dim3(Pp,16), 256, 0, stream>>>(cont, sty, cent32, xsq32, assign);
    k_update64<<<dim3(Pp,8), 256, 0, stream>>>(cont, sty, assign, csum64, cntf);
    k_centupd32<<<NMAT, Cc, 0, stream>>>(csum64, cntf, cent32);
  }
  k_assign_f<<<dim3(Pp,16), 256, 0, stream>>>(cont, sty, cent32, xsq32, assign);

  // ---- stats ----
  k_update64<<<dim3(Pp,8), 256, 0, stream>>>(cont, sty, assign, csum64, cntf);
  k_mu64<<<NMAT, Cc, 0, stream>>>(csum64, cntf, mu64, mu32, dvc32);
  k_covf32<<<dim3(8,8,NMAT), 256, 0, stream>>>(cont, sty, assign, mu32, dvc32, cov32);
  k_power32<<<NMAT, 256, 0, stream>>>(cov32, sarr);
  k_sinv<<<1, 64, 0, stream>>>(sarr, sinv);
  k_sfac<<<1, 32, 0, stream>>>(sarr, sfac);
  k_bias64<<<24, Cc, 0, stream>>>(mu64, bias2);

  // ---- split-bf16 MFMA Newton-Schulz (3-plane early, 2-plane late) + fp32 refine ----
  for (int bt=0; bt<NMAT/NSB16; ++bt){
    int m0 = bt*NSB16;
    int py=0, pz=1, pt=2, sp=3;
    k_initsplit3<<<dim3(NSB16,64), 256, 0, stream>>>(cov32, sarr, st[py], st[pz], PL, m0);
    for (int it=0; it<NSB_ITERS; ++it){
      bool last = (it == NSB_ITERS-1);
      bool full = (it < NS_SWITCH);
      if (full)
        bgemm3<3,false,6><<<dim3(4,4,NSB16), 256, 0, stream>>>(st[pz], st[py], PL, nullptr, st[pt]);
      else
        bgemm3<3,false,3><<<dim3(4,4,NSB16), 256, 0, stream>>>(st[pz], st[py], PL, nullptr, st[pt]);
      if (!last){
        if (full){
          bgemm3<0,false,6><<<dim3(4,4,NSB16), 256, 0, stream>>>(st[py], st[pt], PL, nullptr, st[sp]);
          bgemm3<0,false,6><<<dim3(4,4,NSB16), 256, 0, stream>>>(st[pt], st[pz], PL, nullptr, st[py]);
        } else {
          bgemm3<0,false,3><<<dim3(4,4,NSB16), 256, 0, stream>>>(st[py], st[pt], PL, nullptr, st[sp]);
          bgemm3<0,false,3><<<dim3(4,4,NSB16), 256, 0, stream>>>(st[pt], st[pz], PL, nullptr, st[py]);
        }
        int opy=py, opz=pz;
        py = sp; pz = opy; sp = opz;   // pt unchanged
      } else {
        bgemm3<0,true,3><<<dim3(4,4,NSB16), 256, 0, stream>>>(st[pt], st[pz], PL, spareX, nullptr);
      }
    }
    // fp32 Newton refine: X <- 1.5X - 0.5 X (Ahat X^2), 2 rounds; then Y = Ahat X
    float* X  = spareX;
    float* T1 = R0;
    float* T2 = R1;
    float* T3 = R2;
    for (int r=0; r<2; ++r){
      gemm128<0><<<dim3(4,4,NSB16), 256, 0, stream>>>(X, X, T1, nullptr);
      gemm128<4><<<dim3(4,4,NSB16), 256, 0, stream>>>(cov32 + (size_t)m0*MSZ, T1, T2, sinv + m0);
      gemm128<5><<<dim3(4,4,NSB16), 256, 0, stream>>>(X, T2, T3, nullptr);
      float* tmp = X; X = T3; T3 = tmp;
    }
    gemm128<4><<<dim3(4,4,NSB16), 256, 0, stream>>>(cov32 + (size_t)m0*MSZ, X, T1, sinv + m0);
    k_keep32<<<dim3(NSB16,128), 256, 0, stream>>>(T1, X, nsResC, styAll, m0);
  }

  // ---- G = sfac*(Y_style @ Z_content) + 0.4 I ----
  gemm128<2><<<dim3(4,4,24), 256, 0, stream>>>(styAll, nsResC, G, sfac);

  // ---- apply transform + blend, direct masked write ----
  k_transfer_d<<<dim3(4,32,24), 256, 0, stream>>>(G, cont, assign, mu32, bias2, out);
}

// Round 18
// 12600.860 us; speedup vs baseline: 4.2242x; 1.2659x over previous
//
#include <hip/hip_runtime.h>
#include <math.h>
#include <cstddef>

#define Bn 8
#define Cc 512
#define Nn 4096
#define Kk 3
#define Pp 16
#define NMAT 48
#define MSZ (Cc*Cc)
#define ALPHA_C 0.6f
#define BETA_C 0.4f
#define GAMMA_C 0.1
#define POW_ITERS 8
#define NSB_ITERS 17
#define NS_SWITCH 7
#define NSB16 16

using s8v = __attribute__((ext_vector_type(8))) short;
using f4v = __attribute__((ext_vector_type(4))) float;

__device__ __forceinline__ float b2fs(short u){
  union { unsigned i; float f; } x; x.i = ((unsigned)(unsigned short)u) << 16; return x.f;
}
__device__ __forceinline__ short f2bs(float f){
  unsigned u = __float_as_uint(f);
  unsigned r = (u + 0x7FFF + ((u >> 16) & 1)) >> 16;
  return (short)r;
}

__device__ __forceinline__ const float* Fbase(const float* cont, const float* sty, int p){
  return (p < Bn) ? (cont + (size_t)p*Cc*Nn) : (sty + (size_t)(p-Bn)*Cc*Nn);
}

// ===== ideal-fp32 k-means (round-13 verified arithmetic: DO NOT TOUCH) =====
__global__ void k_init_cent32(const float* __restrict__ cont, const float* __restrict__ sty,
                              float* __restrict__ cent32){
  int m = blockIdx.x; int p = m/Kk, k = m%Kk;
  const int ninit[3] = {0, 2047, 4095};
  const float* F = Fbase(cont, sty, p);
  int c = threadIdx.x;
  cent32[(size_t)m*Cc + c] = F[(size_t)c*Nn + ninit[k]];
}

__global__ __launch_bounds__(256) void k_xsq32(const float* __restrict__ cont, const float* __restrict__ sty,
                                               float* __restrict__ xsq32){
  int p = blockIdx.x;
  int n = blockIdx.y*256 + threadIdx.x;
  const float* F = Fbase(cont, sty, p);
  double s = 0.0;
  for (int c=0; c<Cc; c++){ double v = (double)F[(size_t)c*Nn + n]; s += v*v; }
  xsq32[p*Nn + n] = (float)s;
}

// assign with in-block csq (same sequential fp64 order -> bit-identical trajectory)
__global__ __launch_bounds__(256) void k_assign_f(const float* __restrict__ cont, const float* __restrict__ sty,
                                                  const float* __restrict__ cent32,
                                                  const float* __restrict__ xsq32, int* __restrict__ assign){
  __shared__ float cl[Kk][Cc];
  __shared__ float csqs[Kk];
  int p = blockIdx.x, t = threadIdx.x;
  const float* F = Fbase(cont, sty, p);
  for (int i=t; i<Kk*Cc; i+=256) ((float*)cl)[i] = cent32[(size_t)p*Kk*Cc + i];
  __syncthreads();
  if (t < Kk){
    double s = 0.0;
    for (int i=0;i<Cc;i++){ double v = (double)cl[t][i]; s += v*v; }
    csqs[t] = (float)s;
  }
  __syncthreads();
  float cs0 = csqs[0], cs1 = csqs[1], cs2 = csqs[2];
  int n = blockIdx.y*256 + t;
  const float* col = F + n;
  double d0=0.0, d1=0.0, d2=0.0;
  for (int c=0; c<Cc; c++){
    double f = (double)col[(size_t)c*Nn];
    d0 += f*(double)cl[0][c];
    d1 += f*(double)cl[1][c];
    d2 += f*(double)cl[2][c];
  }
  float f0 = (float)d0, f1 = (float)d1, f2 = (float)d2;
  float xs = xsq32[p*Nn + n];
  float D0, D1, D2;
  {
    #pragma clang fp contract(off)
    D0 = (xs - 2.f*f0) + cs0;
    D1 = (xs - 2.f*f1) + cs1;
    D2 = (xs - 2.f*f2) + cs2;
  }
  int a = 0; float best = D0;
  if (D1 < best){ best = D1; a = 1; }
  if (D2 < best){ best = D2; a = 2; }
  assign[p*Nn + n] = a;
}

__global__ __launch_bounds__(256) void k_update64(const float* __restrict__ cont, const float* __restrict__ sty,
                                                  const int* __restrict__ assign,
                                                  double* __restrict__ csum, float* __restrict__ cntf){
  __shared__ unsigned char al[Nn];
  __shared__ int ri[256];
  int p = blockIdx.x, cg = blockIdx.y, t = threadIdx.x;
  const float* F = Fbase(cont, sty, p);
  for (int i=t; i<Nn; i+=256) al[i] = (unsigned char)assign[p*Nn+i];
  __syncthreads();
  int wave = t>>6, lane = t&63;
  for (int rr=0; rr<16; rr++){
    int r = cg*64 + wave*16 + rr;
    const float* row = F + (size_t)r*Nn;
    double s0=0.0,s1=0.0,s2=0.0;
    for (int n=lane; n<Nn; n+=64){
      double f = (double)row[n]; int a = al[n];
      s0 += (a==0)?f:0.0; s1 += (a==1)?f:0.0; s2 += (a==2)?f:0.0;
    }
    for (int off=32; off>0; off>>=1){
      s0 += __shfl_xor(s0,off); s1 += __shfl_xor(s1,off); s2 += __shfl_xor(s2,off);
    }
    if (lane==0){
      csum[((size_t)p*Kk+0)*Cc + r] = s0;
      csum[((size_t)p*Kk+1)*Cc + r] = s1;
      csum[((size_t)p*Kk+2)*Cc + r] = s2;
    }
  }
  if (cg==0){
    int c0=0,c1=0,c2=0;
    for (int n=t;n<Nn;n+=256){ int a=al[n]; c0+=(a==0); c1+=(a==1); c2+=(a==2); }
    for (int k=0;k<3;k++){
      int v = (k==0)?c0:((k==1)?c1:c2);
      ri[t] = v; __syncthreads();
      for (int off=128; off>0; off>>=1){ if(t<off) ri[t]+=ri[t+off]; __syncthreads(); }
      if (t==0) cntf[p*Kk+k] = (float)ri[0];
      __syncthreads();
    }
  }
}

__global__ void k_centupd32(const double* __restrict__ csum, const float* __restrict__ cntf,
                            float* __restrict__ cent32){
  int m = blockIdx.x, c = threadIdx.x;
  float n = cntf[m];
  if (n > 0.f){
    float s32 = (float)csum[(size_t)m*Cc + c];
    cent32[(size_t)m*Cc + c] = s32 / fmaxf(n, 1.f);
  }
}

__global__ void k_mu64(const double* __restrict__ csum, const float* __restrict__ cntf,
                       double* __restrict__ mu64, float* __restrict__ mu32, float* __restrict__ dvc32){
  int m = blockIdx.x, t = threadIdx.x;
  double n = fmax((double)cntf[m], 1.0);
  double v = csum[(size_t)m*Cc+t] / n;
  mu64[(size_t)m*Cc+t] = v;
  mu32[(size_t)m*Cc+t] = (float)v;
  if (t==0) dvc32[m] = (float)(1.0 / fmax(n-1.0, 1.0));
}

// cov: fp32, lower-triangle blocks only + mirror write. Mask on A side (symmetric).
__global__ __launch_bounds__(256) void k_covf32(const float* __restrict__ cont, const float* __restrict__ sty,
                                                const int* __restrict__ assign, const float* __restrict__ mu32,
                                                const float* __restrict__ dvc32, float* __restrict__ A32){
  if (blockIdx.y > blockIdx.x) return;
  __shared__ float As[16][68], Bs[16][68];
  __shared__ unsigned char al[Nn];
  int m = blockIdx.z; int p = m/Kk; int k = m%Kk;
  const float* F = Fbase(cont, sty, p);
  int t = threadIdx.x;
  for (int i=t; i<Nn; i+=256) al[i] = (unsigned char)assign[p*Nn+i];
  int i0 = blockIdx.x*64, j0 = blockIdx.y*64;
  int lr = t>>2, lc = (t&3)*4;
  int ty = t>>4, tx = t&15;
  const float* muM = mu32 + (size_t)m*Cc;
  float muA = muM[i0+lr];
  float muB = muM[j0+lr];
  __syncthreads();
  float acc[4][4] = {};
  for (int kt=0; kt<Nn; kt+=16){
    float4 av = *(const float4*)(F + (size_t)(i0+lr)*Nn + kt + lc);
    float4 bv = *(const float4*)(F + (size_t)(j0+lr)*Nn + kt + lc);
    float mk[4];
    #pragma unroll
    for (int u=0;u<4;u++) mk[u] = (al[kt+lc+u]==k) ? 1.f : 0.f;
    As[lc+0][lr] = mk[0]*(av.x-muA);
    As[lc+1][lr] = mk[1]*(av.y-muA);
    As[lc+2][lr] = mk[2]*(av.z-muA);
    As[lc+3][lr] = mk[3]*(av.w-muA);
    Bs[lc+0][lr] = bv.x-muB;
    Bs[lc+1][lr] = bv.y-muB;
    Bs[lc+2][lr] = bv.z-muB;
    Bs[lc+3][lr] = bv.w-muB;
    __syncthreads();
    #pragma unroll
    for (int kk=0; kk<16; kk++){
      float aa[4], bb[4];
      #pragma unroll
      for (int i=0;i<4;i++) aa[i] = As[kk][ty*4+i];
      #pragma unroll
      for (int j=0;j<4;j++) bb[j] = Bs[kk][tx*4+j];
      #pragma unroll
      for (int i=0;i<4;i++)
        #pragma unroll
        for (int j=0;j<4;j++) acc[i][j] = fmaf(aa[i], bb[j], acc[i][j]);
    }
    __syncthreads();
  }
  float dv = dvc32[m];
  #pragma unroll
  for (int i=0;i<4;i++){
    int gi = i0 + ty*4 + i;
    #pragma unroll
    for (int j=0;j<4;j++){
      int gj = j0 + tx*4 + j;
      float v = acc[i][j]*dv;
      if (gi==gj) v += (float)GAMMA_C;
      A32[(size_t)m*MSZ + (size_t)gi*Cc + gj] = v;
      A32[(size_t)m*MSZ + (size_t)gj*Cc + gi] = v;
    }
  }
}

// ===== distributed power iteration (s-invariant; parallel matvec) =====
__global__ void k_pinit(double* __restrict__ pv){
  int m = blockIdx.x, t = threadIdx.x;
  for (int i=t; i<Cc; i+=256) pv[(size_t)m*Cc + i] = 1.0;
}

// grid (NMAT, 32): each wave handles 4 rows with coalesced 64-lane dots
__global__ __launch_bounds__(256) void k_matvec(const float* __restrict__ A32, const double* __restrict__ pv,
                                                double* __restrict__ pw){
  int m = blockIdx.x, by = blockIdx.y, t = threadIdx.x;
  const float* A = A32 + (size_t)m*MSZ;
  const double* vm = pv + (size_t)m*Cc;
  int wv = t>>6, lane = t&63;
  #pragma unroll
  for (int rr=0; rr<4; rr++){
    int r = by*16 + wv*4 + rr;
    const float* row = A + (size_t)r*Cc;
    double s = 0.0;
    #pragma unroll
    for (int j=0; j<8; j++) s += (double)row[lane + j*64] * vm[lane + j*64];
    for (int off=32; off>0; off>>=1) s += __shfl_xor(s, off);
    if (lane==0) pw[(size_t)m*Cc + r] = s;
  }
}

__global__ __launch_bounds__(256) void k_pnorm(const double* __restrict__ pw, double* __restrict__ pv){
  __shared__ double red[256];
  int m = blockIdx.x, t = threadIdx.x;
  double nn = 0.0;
  for (int i=t; i<Cc; i+=256){ double w = pw[(size_t)m*Cc + i]; nn += w*w; }
  red[t] = nn; __syncthreads();
  for (int off=128; off>0; off>>=1){ if (t<off) red[t]+=red[t+off]; __syncthreads(); }
  double inv = rsqrt(fmax(red[0], 1e-300));
  for (int i=t; i<Cc; i+=256) pv[(size_t)m*Cc + i] = pw[(size_t)m*Cc + i]*inv;
}

__global__ __launch_bounds__(256) void k_rayleigh(const double* __restrict__ pv, const double* __restrict__ pw,
                                                  float* __restrict__ sarr, float* __restrict__ sinv){
  __shared__ double red[256];
  int m = blockIdx.x, t = threadIdx.x;
  double rr = 0.0;
  for (int i=t; i<Cc; i+=256) rr += pv[(size_t)m*Cc + i]*pw[(size_t)m*Cc + i];
  red[t] = rr; __syncthreads();
  for (int off=128; off>0; off>>=1){ if (t<off) red[t]+=red[t+off]; __syncthreads(); }
  if (t==0){
    float s = (float)(1.3*red[0] + 1e-6);
    sarr[m] = s;
    sinv[m] = 1.f/s;
  }
}

// init NS: Y0 = cov/s (3-way bf16 split), Z0 = I (3-way)
__global__ __launch_bounds__(256) void k_initsplit3(const float* __restrict__ cov32, const float* __restrict__ sarr,
                                                    short* __restrict__ Y, short* __restrict__ Z,
                                                    size_t PL, int m0){
  int i = blockIdx.x, t = threadIdx.x;
  float rs = 1.f / sarr[m0+i];
  const float* src = cov32 + (size_t)(m0+i)*MSZ;
  size_t base = (size_t)i*MSZ;
  int j0 = blockIdx.y*4096;
  for (int j = j0 + t; j < j0 + 4096; j += 256){
    float v = src[j]*rs;
    short h = f2bs(v);  float r1 = v - b2fs(h);
    short md = f2bs(r1); float r2 = r1 - b2fs(md);
    short lo = f2bs(r2);
    Y[base+j] = h; Y[base+j+PL] = md; Y[base+j+2*PL] = lo;
    int rr = j>>9, cc = j&511;
    Z[base+j]      = (rr==cc) ? (short)0x3F80 : (short)0;
    Z[base+j+PL]   = 0;
    Z[base+j+2*PL] = 0;
  }
}

// split-bf16 MFMA batched GEMM, 128x128 tile, 4 waves, K-step 32.
// NPROD=6: 3-plane. NPROD=3: 2-plane. MODE 3: C = 1.5I - 0.5*(A@B).
template<int MODE, bool WF, int NPROD>
__global__ __launch_bounds__(256) void bgemm3(const short* __restrict__ A3, const short* __restrict__ B3,
                                              size_t PL, float* __restrict__ Cf, short* __restrict__ C3){
  __shared__ short lA[3][128][40], lB[3][128][40];
  const int NPL = (NPROD==6) ? 3 : 2;
  int m = blockIdx.z;
  size_t mb = (size_t)m*MSZ;
  int t = threadIdx.x;
  int i0 = blockIdx.x*128, j0 = blockIdx.y*128;
  int w = t>>6, lane = t&63;
  int wm = w>>1, wn = w&1;
  int fr = lane&15, kq = lane>>4;
  int sr = t>>1, sk = (t&1)*16;
  f4v acc[4][4];
  #pragma unroll
  for (int i=0;i<4;i++)
    #pragma unroll
    for (int j=0;j<4;j++){ f4v z = {0.f,0.f,0.f,0.f}; acc[i][j] = z; }
  const short* ga = A3 + mb + (size_t)(i0+sr)*Cc + sk;
  const short* gb = B3 + mb + (size_t)(j0+sr)*Cc + sk;
  for (int kt=0; kt<Cc; kt+=32){
    #pragma unroll
    for (int pl=0; pl<NPL; pl++){
      *(s8v*)&lA[pl][sr][sk]   = *(const s8v*)(ga + (size_t)pl*PL + kt);
      *(s8v*)&lA[pl][sr][sk+8] = *(const s8v*)(ga + (size_t)pl*PL + kt + 8);
      *(s8v*)&lB[pl][sr][sk]   = *(const s8v*)(gb + (size_t)pl*PL + kt);
      *(s8v*)&lB[pl][sr][sk+8] = *(const s8v*)(gb + (size_t)pl*PL + kt + 8);
    }
    __syncthreads();
    s8v bh[4], bm[4], bl[4];
    #pragma unroll
    for (int nt=0;nt<4;nt++){
      bh[nt] = *(const s8v*)&lB[0][wn*64+nt*16+fr][kq*8];
      bm[nt] = *(const s8v*)&lB[1][wn*64+nt*16+fr][kq*8];
      if (NPROD==6) bl[nt] = *(const s8v*)&lB[2][wn*64+nt*16+fr][kq*8];
    }
    #pragma unroll
    for (int mt=0;mt<4;mt++){
      s8v ah = *(const s8v*)&lA[0][wm*64+mt*16+fr][kq*8];
      s8v am = *(const s8v*)&lA[1][wm*64+mt*16+fr][kq*8];
      s8v al;
      if (NPROD==6) al = *(const s8v*)&lA[2][wm*64+mt*16+fr][kq*8];
      #pragma unroll
      for (int nt=0;nt<4;nt++){
        acc[mt][nt] = __builtin_amdgcn_mfma_f32_16x16x32_bf16(ah, bh[nt], acc[mt][nt], 0,0,0);
        acc[mt][nt] = __builtin_amdgcn_mfma_f32_16x16x32_bf16(ah, bm[nt], acc[mt][nt], 0,0,0);
        acc[mt][nt] = __builtin_amdgcn_mfma_f32_16x16x32_bf16(am, bh[nt], acc[mt][nt], 0,0,0);
        if (NPROD==6){
          acc[mt][nt] = __builtin_amdgcn_mfma_f32_16x16x32_bf16(ah, bl[nt], acc[mt][nt], 0,0,0);
          acc[mt][nt] = __builtin_amdgcn_mfma_f32_16x16x32_bf16(al, bh[nt], acc[mt][nt], 0,0,0);
          acc[mt][nt] = __builtin_amdgcn_mfma_f32_16x16x32_bf16(am, bm[nt], acc[mt][nt], 0,0,0);
        }
      }
    }
    __syncthreads();
  }
  #pragma unroll
  for (int mt=0;mt<4;mt++){
    #pragma unroll
    for (int nt=0;nt<4;nt++){
      int gj = j0 + wn*64 + nt*16 + fr;
      #pragma unroll
      for (int j=0;j<4;j++){
        int gi = i0 + wm*64 + mt*16 + kq*4 + j;
        float v = acc[mt][nt][j];
        if (MODE==3) v = -0.5f*v + ((gi==gj)?1.5f:0.f);
        size_t idx = mb + (size_t)gi*Cc + gj;
        if (WF) Cf[idx] = v;
        else {
          short h = f2bs(v);  float r1 = v - b2fs(h);
          short md = f2bs(r1);
          C3[idx] = h; C3[idx+PL] = md;
          if (NPROD==6){ float r2 = r1 - b2fs(md); C3[idx+2*PL] = f2bs(r2); }
        }
      }
    }
  }
}

// fp32 batched GEMM 128x128, 8x8 micro.
// MODE 0: C=A@B  MODE 2: C=sfac[m]*(A@B)+0.4I  MODE 4: C=sfac[m]*(A@B)  MODE 5: C=1.5A-0.5(A@B)
template<int MODE>
__global__ __launch_bounds__(256) void gemm128(const float* __restrict__ Ab, const float* __restrict__ Bb,
                                               float* __restrict__ Cb, const float* __restrict__ sfac){
  __shared__ float As[16][132], Bs[16][132];
  int m = blockIdx.z;
  const float* A = Ab + (size_t)m*MSZ;
  const float* Bm = Bb + (size_t)m*MSZ;
  float* Cm = Cb + (size_t)m*MSZ;
  int t = threadIdx.x;
  int tx = t&15, ty = t>>4;
  int i0 = blockIdx.x*128, j0 = blockIdx.y*128;
  int ar = t>>2, ac = (t&3)*4;
  int bk = t>>5, bj = (t&31)*4;
  float acc[8][8] = {};
  for (int kt=0; kt<Cc; kt+=16){
    float4 a0 = *(const float4*)(A + (size_t)(i0+ar)*Cc + kt + ac);
    float4 a1 = *(const float4*)(A + (size_t)(i0+ar+64)*Cc + kt + ac);
    float4 b0 = *(const float4*)(Bm + (size_t)(kt+bk)*Cc + j0 + bj);
    float4 b1 = *(const float4*)(Bm + (size_t)(kt+bk+8)*Cc + j0 + bj);
    As[ac+0][ar]=a0.x; As[ac+1][ar]=a0.y; As[ac+2][ar]=a0.z; As[ac+3][ar]=a0.w;
    As[ac+0][ar+64]=a1.x; As[ac+1][ar+64]=a1.y; As[ac+2][ar+64]=a1.z; As[ac+3][ar+64]=a1.w;
    *(float4*)&Bs[bk][bj] = b0;
    *(float4*)&Bs[bk+8][bj] = b1;
    __syncthreads();
    #pragma unroll
    for (int kk=0; kk<16; kk++){
      float4 x0 = *(const float4*)&As[kk][ty*8];
      float4 x1 = *(const float4*)&As[kk][ty*8+4];
      float4 y0 = *(const float4*)&Bs[kk][tx*8];
      float4 y1 = *(const float4*)&Bs[kk][tx*8+4];
      float av[8] = {x0.x,x0.y,x0.z,x0.w,x1.x,x1.y,x1.z,x1.w};
      float bv[8] = {y0.x,y0.y,y0.z,y0.w,y1.x,y1.y,y1.z,y1.w};
      #pragma unroll
      for (int i=0;i<8;i++)
        #pragma unroll
        for (int j=0;j<8;j++) acc[i][j] = fmaf(av[i], bv[j], acc[i][j]);
    }
    __syncthreads();
  }
  float sf = (MODE==2 || MODE==4) ? sfac[m] : 0.f;
  #pragma unroll
  for (int i=0;i<8;i++){
    int gi = i0 + ty*8 + i;
    #pragma unroll
    for (int j=0;j<8;j++){
      int gj = j0 + tx*8 + j;
      float pv = acc[i][j];
      float v;
      if (MODE==2)      v = sf*pv + ((gi==gj)?BETA_C:0.f);
      else if (MODE==4) v = sf*pv;
      else if (MODE==5) v = 1.5f*A[(size_t)gi*Cc + gj] - 0.5f*pv;
      else              v = pv;
      Cm[(size_t)gi*Cc + gj] = v;
    }
  }
}

__global__ __launch_bounds__(256) void k_keep32(const float* __restrict__ Yb, const float* __restrict__ Zb,
                                                float* __restrict__ nsResC, float* __restrict__ styAll, int m0){
  int i = blockIdx.x, t = threadIdx.x;
  int mm = m0 + i;
  const float* src = (mm < 24) ? (Zb + (size_t)i*MSZ) : (Yb + (size_t)i*MSZ);
  float* dst = (mm < 24) ? (nsResC + (size_t)mm*MSZ) : (styAll + (size_t)(mm-24)*MSZ);
  int j0 = blockIdx.y*2048;
  for (int j = j0 + t; j < j0 + 2048; j += 256) dst[j] = src[j];
}

__global__ void k_sfac(const float* __restrict__ sarr, float* __restrict__ sfac){
  int t = threadIdx.x;
  if (t < 24) sfac[t] = ALPHA_C * sqrtf(sarr[24+t] / sarr[t]);
}

__global__ void k_bias64(const double* __restrict__ mu64, float* __restrict__ bias2){
  int m2 = blockIdx.x, t = threadIdx.x;
  bias2[(size_t)m2*Cc + t] = (float)(0.6*mu64[(size_t)(24+m2)*Cc + t] + 0.4*mu64[(size_t)m2*Cc + t]);
}

__global__ __launch_bounds__(256) void k_transfer_d(const float* __restrict__ G, const float* __restrict__ cont,
                                                    const int* __restrict__ assign, const float* __restrict__ mu,
                                                    const float* __restrict__ bias2, float* __restrict__ out){
  __shared__ float As[16][132], Bs[16][132];
  __shared__ unsigned char al2[128];
  int m2 = blockIdx.z; int b = m2/Kk; int k = m2%Kk;
  const float* A = G + (size_t)m2*MSZ;
  const float* F = cont + (size_t)b*Cc*Nn;
  const float* muM = mu + (size_t)m2*Cc;
  int t = threadIdx.x;
  int i0 = blockIdx.x*128, j0 = blockIdx.y*128;
  int ar = t>>2, ac = (t&3)*4;
  int bk = t>>5, bj = (t&31)*4;
  int tx = t&15, ty = t>>4;
  if (t < 128) al2[t] = (unsigned char)assign[b*Nn + j0 + t];
  __syncthreads();
  float acc[8][8] = {};
  for (int kt=0; kt<Cc; kt+=16){
    float4 a0 = *(const float4*)(A + (size_t)(i0+ar)*Cc + kt + ac);
    float4 a1 = *(const float4*)(A + (size_t)(i0+ar+64)*Cc + kt + ac);
    float mb0 = muM[kt+bk], mb1 = muM[kt+bk+8];
    float4 b0 = *(const float4*)(F + (size_t)(kt+bk)*Nn + j0 + bj);
    float4 b1 = *(const float4*)(F + (size_t)(kt+bk+8)*Nn + j0 + bj);
    As[ac+0][ar]=a0.x; As[ac+1][ar]=a0.y; As[ac+2][ar]=a0.z; As[ac+3][ar]=a0.w;
    As[ac+0][ar+64]=a1.x; As[ac+1][ar+64]=a1.y; As[ac+2][ar+64]=a1.z; As[ac+3][ar+64]=a1.w;
    Bs[bk][bj+0]=b0.x-mb0; Bs[bk][bj+1]=b0.y-mb0; Bs[bk][bj+2]=b0.z-mb0; Bs[bk][bj+3]=b0.w-mb0;
    Bs[bk+8][bj+0]=b1.x-mb1; Bs[bk+8][bj+1]=b1.y-mb1; Bs[bk+8][bj+2]=b1.z-mb1; Bs[bk+8][bj+3]=b1.w-mb1;
    __syncthreads();
    #pragma unroll
    for (int kk=0; kk<16; kk++){
      float4 x0 = *(const float4*)&As[kk][ty*8];
      float4 x1 = *(const float4*)&As[kk][ty*8+4];
      float4 y0 = *(const float4*)&Bs[kk][tx*8];
      float4 y1 = *(const float4*)&Bs[kk][tx*8+4];
      float av[8] = {x0.x,x0.y,x0.z,x0.w,x1.x,x1.y,x1.z,x1.w};
      float bv[8] = {y0.x,y0.y,y0.z,y0.w,y1.x,y1.y,y1.z,y1.w};
      #pragma unroll
      for (int i=0;i<8;i++)
        #pragma unroll
        for (int j=0;j<8;j++) acc[i][j] = fmaf(av[i], bv[j], acc[i][j]);
    }
    __syncthreads();
  }
  #pragma unroll
  for (int j=0;j<8;j++){
    int lc2 = tx*8 + j;
    if (al2[lc2] != k) continue;
    int gj = j0 + lc2;
    #pragma unroll
    for (int i=0;i<8;i++){
      int gi = i0 + ty*8 + i;
      out[((size_t)b*Cc + gi)*Nn + gj] = acc[i][j] + bias2[(size_t)m2*Cc + gi];
    }
  }
}

extern "C" void kernel_launch(void* const* d_in, const int* in_sizes, int n_in,
                              void* d_out, int out_size, void* d_ws, size_t ws_size,
                              hipStream_t stream){
  const float* cont = (const float*)d_in[0];
  const float* sty  = (const float*)d_in[1];
  float* out = (float*)d_out;

  char* w = (char*)d_ws;
  size_t off = 0;
  auto alloc = [&](size_t bytes) -> void* {
    void* pp = (void*)(w + off);
    off = (off + bytes + 255) & ~(size_t)255;
    return pp;
  };
  float*  cent32 = (float*) alloc((size_t)NMAT*Cc*4);
  float*  xsq32  = (float*) alloc((size_t)Pp*Nn*4);
  double* csum64 = (double*)alloc((size_t)NMAT*Cc*8);
  float*  cntf   = (float*) alloc((size_t)NMAT*4);
  double* mu64   = (double*)alloc((size_t)NMAT*Cc*8);
  float*  mu32   = (float*) alloc((size_t)NMAT*Cc*4);
  float*  dvc32  = (float*) alloc((size_t)NMAT*4);
  double* pv     = (double*)alloc((size_t)NMAT*Cc*8);
  double* pw     = (double*)alloc((size_t)NMAT*Cc*8);
  float*  sarr   = (float*) alloc((size_t)NMAT*4);
  float*  sinv   = (float*) alloc((size_t)NMAT*4);
  float*  sfac   = (float*) alloc((size_t)24*4);
  float*  bias2  = (float*) alloc((size_t)24*Cc*4);
  int*    assign = (int*)   alloc((size_t)Pp*Nn*4);
  float*  G      = (float*) alloc((size_t)24*MSZ*4);   // 24 MiB (doubles as NS state C)
  float*  nsResC = (float*) alloc((size_t)24*MSZ*4);   // 24 MiB
  float*  styAll = (float*) alloc((size_t)24*MSZ*4);   // 24 MiB
  float*  cov32  = (float*) alloc((size_t)NMAT*MSZ*4); // 48 MiB
  short*  nsX    = (short*) alloc((size_t)3*NSB16*MSZ*2); // 24 MiB (NS state D)
  (void)ws_size; (void)in_sizes; (void)n_in; (void)out_size;

  // d_out 64 MiB: NS states A (0..24MiB), B (24..48MiB), fp32 X spare (48..64MiB).
  // During refine the dead state regions become fp32 temps R0/R1/R2.
  const size_t PL = (size_t)NSB16*MSZ;   // shorts per plane (8 MiB)
  char* db = (char*)d_out;
  short* st[4];
  st[0] = (short*)db;
  st[1] = (short*)(db + (size_t)24*1024*1024);
  st[2] = (short*)G;
  st[3] = nsX;
  float* spareX = (float*)(db + (size_t)48*1024*1024);
  float* R0 = (float*)db;
  float* R1 = (float*)(db + (size_t)16*1024*1024);
  float* R2 = (float*)(db + (size_t)32*1024*1024);

  // ---- ideal-fp32 k-means ----
  k_init_cent32<<<NMAT, Cc, 0, stream>>>(cont, sty, cent32);
  k_xsq32<<<dim3(Pp,16), 256, 0, stream>>>(cont, sty, xsq32);
  for (int it=0; it<10; ++it){
    k_assign_f<<<dim3(Pp,16), 256, 0, stream>>>(cont, sty, cent32, xsq32, assign);
    k_update64<<<dim3(Pp,8), 256, 0, stream>>>(cont, sty, assign, csum64, cntf);
    k_centupd32<<<NMAT, Cc, 0, stream>>>(csum64, cntf, cent32);
  }
  k_assign_f<<<dim3(Pp,16), 256, 0, stream>>>(cont, sty, cent32, xsq32, assign);

  // ---- stats ----
  k_update64<<<dim3(Pp,8), 256, 0, stream>>>(cont, sty, assign, csum64, cntf);
  k_mu64<<<NMAT, Cc, 0, stream>>>(csum64, cntf, mu64, mu32, dvc32);
  k_covf32<<<dim3(8,8,NMAT), 256, 0, stream>>>(cont, sty, assign, mu32, dvc32, cov32);

  // ---- distributed power iteration ----
  k_pinit<<<NMAT, 256, 0, stream>>>(pv);
  for (int it=0; it<POW_ITERS+1; ++it){
    k_matvec<<<dim3(NMAT,32), 256, 0, stream>>>(cov32, pv, pw);
    if (it < POW_ITERS) k_pnorm<<<NMAT, 256, 0, stream>>>(pw, pv);
  }
  k_rayleigh<<<NMAT, 256, 0, stream>>>(pv, pw, sarr, sinv);
  k_sfac<<<1, 32, 0, stream>>>(sarr, sfac);
  k_bias64<<<24, Cc, 0, stream>>>(mu64, bias2);

  // ---- split-bf16 MFMA Newton-Schulz (3-plane early, 2-plane late) + fp32 refine ----
  for (int bt=0; bt<NMAT/NSB16; ++bt){
    int m0 = bt*NSB16;
    int py=0, pz=1, pt=2, sp=3;
    k_initsplit3<<<dim3(NSB16,64), 256, 0, stream>>>(cov32, sarr, st[py], st[pz], PL, m0);
    for (int it=0; it<NSB_ITERS; ++it){
      bool last = (it == NSB_ITERS-1);
      bool full = (it < NS_SWITCH);
      if (full)
        bgemm3<3,false,6><<<dim3(4,4,NSB16), 256, 0, stream>>>(st[pz], st[py], PL, nullptr, st[pt]);
      else
        bgemm3<3,false,3><<<dim3(4,4,NSB16), 256, 0, stream>>>(st[pz], st[py], PL, nullptr, st[pt]);
      if (!last){
        if (full){
          bgemm3<0,false,6><<<dim3(4,4,NSB16), 256, 0, stream>>>(st[py], st[pt], PL, nullptr, st[sp]);
          bgemm3<0,false,6><<<dim3(4,4,NSB16), 256, 0, stream>>>(st[pt], st[pz], PL, nullptr, st[py]);
        } else {
          bgemm3<0,false,3><<<dim3(4,4,NSB16), 256, 0, stream>>>(st[py], st[pt], PL, nullptr, st[sp]);
          bgemm3<0,false,3><<<dim3(4,4,NSB16), 256, 0, stream>>>(st[pt], st[pz], PL, nullptr, st[py]);
        }
        int opy=py, opz=pz;
        py = sp; pz = opy; sp = opz;   // pt unchanged
      } else {
        bgemm3<0,true,3><<<dim3(4,4,NSB16), 256, 0, stream>>>(st[pt], st[pz], PL, spareX, nullptr);
      }
    }
    // fp32 Newton refine: X <- 1.5X - 0.5 X (Ahat X^2), 1 round; then Y = Ahat X
    float* X  = spareX;
    float* T1 = R0;
    float* T2 = R1;
    float* T3 = R2;
    gemm128<0><<<dim3(4,4,NSB16), 256, 0, stream>>>(X, X, T1, nullptr);
    gemm128<4><<<dim3(4,4,NSB16), 256, 0, stream>>>(cov32 + (size_t)m0*MSZ, T1, T2, sinv + m0);
    gemm128<5><<<dim3(4,4,NSB16), 256, 0, stream>>>(X, T2, T3, nullptr);
    X = T3;
    gemm128<4><<<dim3(4,4,NSB16), 256, 0, stream>>>(cov32 + (size_t)m0*MSZ, X, T1, sinv + m0);
    k_keep32<<<dim3(NSB16,128), 256, 0, stream>>>(T1, X, nsResC, styAll, m0);
  }

  // ---- G = sfac*(Y_style @ Z_content) + 0.4 I ----
  gemm128<2><<<dim3(4,4,24), 256, 0, stream>>>(styAll, nsResC, G, sfac);

  // ---- apply transform + blend, direct masked write ----
  k_transfer_d<<<dim3(4,32,24), 256, 0, stream>>>(G, cont, assign, mu32, bias2, out);
}